// Round 1
// baseline (725.390 us; speedup 1.0000x reference)
//
#include <hip/hip_runtime.h>
#include <hip/hip_bf16.h>
#include <cstdint>
#include <cstddef>

// Problem constants (match reference)
#define N_NODES  20000
#define N_EDGES  320000
#define E_TOTAL  (N_EDGES + N_NODES)   // with self loops = 340000
#define N_GRAPHS 256
#define F_NODE   11
#define F_TDA    30
#define DIM      128
#define NHEAD    4
#define NLAYER   3
#define NTASK    6
#define NEG_SLOPE 0.2f
#define LN_EPS   1e-5f

// ---------------------------------------------------------------------------
// CSR construction (dst-grouped) — rebuilt every call (no static state)
// ---------------------------------------------------------------------------
__global__ void count_kernel(const int* __restrict__ edge_index, int* __restrict__ counts) {
    int e = blockIdx.x * 256 + threadIdx.x;
    if (e >= E_TOTAL) return;
    int d = (e < N_EDGES) ? edge_index[N_EDGES + e] : (e - N_EDGES);
    atomicAdd(&counts[d], 1);
}

__global__ void scan_kernel(const int* __restrict__ counts, int* __restrict__ row_ptr,
                            int* __restrict__ cursor, int n) {
    __shared__ int buf[1024];
    __shared__ int carry_s;
    int tid = threadIdx.x;
    if (tid == 0) carry_s = 0;
    __syncthreads();
    for (int base = 0; base < n; base += 1024) {
        int i = base + tid;
        int v = (i < n) ? counts[i] : 0;
        buf[tid] = v;
        __syncthreads();
        for (int s = 1; s < 1024; s <<= 1) {
            int t = (tid >= s) ? buf[tid - s] : 0;
            __syncthreads();
            buf[tid] += t;
            __syncthreads();
        }
        int excl = buf[tid] - v;
        int tot  = buf[1023];
        if (i < n) { int r = carry_s + excl; row_ptr[i] = r; cursor[i] = r; }
        __syncthreads();
        if (tid == 0) carry_s += tot;
        __syncthreads();
    }
    if (tid == 0) row_ptr[n] = carry_s;
}

__global__ void scatter_kernel(const int* __restrict__ edge_index, int* __restrict__ cursor,
                               int* __restrict__ csr_src) {
    int e = blockIdx.x * 256 + threadIdx.x;
    if (e >= E_TOTAL) return;
    int s, d;
    if (e < N_EDGES) { s = edge_index[e]; d = edge_index[N_EDGES + e]; }
    else             { s = e - N_EDGES;   d = s; }
    int pos = atomicAdd(&cursor[d], 1);
    csr_src[pos] = s;
}

// ---------------------------------------------------------------------------
// Input projection: h = relu(x @ w_in + b_in)   [N,11] @ [11,128]
// ---------------------------------------------------------------------------
__global__ __launch_bounds__(128) void proj_in_kernel(const float* __restrict__ x,
                                                      const float* __restrict__ w,
                                                      const float* __restrict__ b,
                                                      float* __restrict__ h) {
    __shared__ float xr[F_NODE];
    int n = blockIdx.x, d = threadIdx.x;
    if (d < F_NODE) xr[d] = x[n * F_NODE + d];
    __syncthreads();
    float acc = b[d];
#pragma unroll
    for (int k = 0; k < F_NODE; k++) acc += xr[k] * w[k * DIM + d];
    h[(size_t)n * DIM + d] = fmaxf(acc, 0.f);
}

// ---------------------------------------------------------------------------
// GEMM: hh = h @ W   [M,128] @ [128,512] -> [M,512]
// 64x64 tile, 256 threads, 4x4 per-thread micro-tile, K chunked by 32.
// ---------------------------------------------------------------------------
__global__ __launch_bounds__(256) void gemm_hh_kernel(const float* __restrict__ A,
                                                      const float* __restrict__ W,
                                                      float* __restrict__ C, int M) {
    __shared__ float As[32][65];   // [k][m], +1 pad avoids write conflicts
    __shared__ float Bs[32][64];   // [k][n]
    int tid = threadIdx.x;
    int tx = tid & 15, ty = tid >> 4;
    int m0 = blockIdx.y << 6, n0 = blockIdx.x << 6;
    float c[4][4] = {};
    for (int kk = 0; kk < 128; kk += 32) {
        int lk = tid & 31, lm0 = tid >> 5;  // A: 32 k-cols x 8 rows per pass
#pragma unroll
        for (int p = 0; p < 8; p++) {
            int m = lm0 + p * 8;
            int row = m0 + m;
            As[lk][m] = (row < M) ? A[(size_t)row * 128 + kk + lk] : 0.f;
        }
        int ln = tid & 63, lkb = tid >> 6;  // B: 64 n-cols x 4 k per pass
#pragma unroll
        for (int p = 0; p < 8; p++) {
            int k = lkb + p * 4;
            Bs[k][ln] = W[(size_t)(kk + k) * 512 + n0 + ln];
        }
        __syncthreads();
#pragma unroll
        for (int k = 0; k < 32; k++) {
            float a0 = As[k][ty * 4 + 0], a1 = As[k][ty * 4 + 1];
            float a2 = As[k][ty * 4 + 2], a3 = As[k][ty * 4 + 3];
            float4 bv = *(const float4*)&Bs[k][tx * 4];
            c[0][0] += a0 * bv.x; c[0][1] += a0 * bv.y; c[0][2] += a0 * bv.z; c[0][3] += a0 * bv.w;
            c[1][0] += a1 * bv.x; c[1][1] += a1 * bv.y; c[1][2] += a1 * bv.z; c[1][3] += a1 * bv.w;
            c[2][0] += a2 * bv.x; c[2][1] += a2 * bv.y; c[2][2] += a2 * bv.z; c[2][3] += a2 * bv.w;
            c[3][0] += a3 * bv.x; c[3][1] += a3 * bv.y; c[3][2] += a3 * bv.z; c[3][3] += a3 * bv.w;
        }
        __syncthreads();
    }
#pragma unroll
    for (int i = 0; i < 4; i++) {
        int row = m0 + ty * 4 + i;
        if (row < M) {
            float4 v = make_float4(c[i][0], c[i][1], c[i][2], c[i][3]);
            *(float4*)&C[(size_t)row * 512 + n0 + tx * 4] = v;
        }
    }
}

// ---------------------------------------------------------------------------
// alpha_s[n,h] = <hh[n,h,:], a_src[h,:]> ; alpha_d likewise. 1 wave per (n,h).
// ---------------------------------------------------------------------------
__global__ __launch_bounds__(256) void alpha_kernel(const float* __restrict__ hh,
                                                    const float* __restrict__ a_s,
                                                    const float* __restrict__ a_d,
                                                    float* __restrict__ out_s,
                                                    float* __restrict__ out_d) {
    int n = blockIdx.x;
    int h = threadIdx.x >> 6;
    int lane = threadIdx.x & 63;
    const float* base = hh + (size_t)n * 512 + h * 128 + lane * 2;
    float2 v = *(const float2*)base;
    float ss = v.x * a_s[h * 128 + lane * 2] + v.y * a_s[h * 128 + lane * 2 + 1];
    float sd = v.x * a_d[h * 128 + lane * 2] + v.y * a_d[h * 128 + lane * 2 + 1];
#pragma unroll
    for (int off = 32; off; off >>= 1) { ss += __shfl_xor(ss, off); sd += __shfl_xor(sd, off); }
    if (lane == 0) { out_s[n * 4 + h] = ss; out_d[n * 4 + h] = sd; }
}

// ---------------------------------------------------------------------------
// Per-dst-node GAT tail: edge softmax + message aggregation + head mean
// + bias + LayerNorm + ReLU + residual.  One block (256 thr) per node.
// ---------------------------------------------------------------------------
__global__ __launch_bounds__(256) void gat_aggregate_kernel(
    const float* __restrict__ hh, const float* __restrict__ al_s,
    const float* __restrict__ al_d, const int* __restrict__ row_ptr,
    const int* __restrict__ csr_src, const float* __restrict__ h_in,
    const float* __restrict__ b_gat, const float* __restrict__ ln_w,
    const float* __restrict__ ln_b, float* __restrict__ h_out) {
    __shared__ float s_red[256];
    __shared__ float m_h[4], l_h[4];
    __shared__ float w_chunk[64][4];
    __shared__ int   src_chunk[64];

    int n = blockIdx.x;
    int tid = threadIdx.x;
    int begin = row_ptr[n], end = row_ptr[n + 1];
    int deg = end - begin;             // >= 1 (self loop)
    int h4 = tid & 3;                  // stride-256 loop keeps h fixed per thread
    float ad = al_d[n * 4 + h4];

    // phase 1: per-head max of leaky_relu(alpha_s[src]+alpha_d[n])
    float lm = -1e30f;
    for (int i = tid; i < deg * 4; i += 256) {
        int e = i >> 2;
        int s = csr_src[begin + e];
        float v = al_s[s * 4 + h4] + ad;
        v = (v > 0.f) ? v : NEG_SLOPE * v;
        lm = fmaxf(lm, v);
    }
    s_red[tid] = lm; __syncthreads();
    for (int s = 128; s >= 4; s >>= 1) { if (tid < s) s_red[tid] = fmaxf(s_red[tid], s_red[tid + s]); __syncthreads(); }
    if (tid < 4) m_h[tid] = s_red[tid];
    __syncthreads();

    // phase 2: per-head sum of exp
    float mh = m_h[h4];
    float ls = 0.f;
    for (int i = tid; i < deg * 4; i += 256) {
        int e = i >> 2;
        int s = csr_src[begin + e];
        float v = al_s[s * 4 + h4] + ad;
        v = (v > 0.f) ? v : NEG_SLOPE * v;
        ls += __expf(v - mh);
    }
    s_red[tid] = ls; __syncthreads();
    for (int s = 128; s >= 4; s >>= 1) { if (tid < s) s_red[tid] += s_red[tid + s]; __syncthreads(); }
    if (tid < 4) l_h[tid] = s_red[tid];
    __syncthreads();

    // phase 3: weighted aggregation; thread owns f=tid and f=tid+256 of [H*D]
    float inv_l = 1.f / l_h[h4];
    int hA = tid >> 7;                  // 0/1
    float acc0 = 0.f, acc1 = 0.f;
    for (int cb = 0; cb < deg; cb += 64) {
        int ce = min(64, deg - cb);
        if (tid < ce * 4) {
            int e = tid >> 2;
            int s = csr_src[begin + cb + e];
            if (h4 == 0) src_chunk[e] = s;
            float v = al_s[s * 4 + h4] + ad;
            v = (v > 0.f) ? v : NEG_SLOPE * v;
            w_chunk[e][h4] = __expf(v - mh) * inv_l;
        }
        __syncthreads();
        for (int e = 0; e < ce; e++) {
            int s = src_chunk[e];
            const float* hr = hh + (size_t)s * 512;
            acc0 += w_chunk[e][hA]     * hr[tid];
            acc1 += w_chunk[e][2 + hA] * hr[tid + 256];
        }
        __syncthreads();
    }

    // head mean + bias
    s_red[tid] = acc0 + acc1;
    __syncthreads();
    float g = 0.f;
    if (tid < 128) g = (s_red[tid] + s_red[tid + 128]) * 0.25f + b_gat[tid];
    __syncthreads();

    // LayerNorm over 128 features
    s_red[tid] = (tid < 128) ? g : 0.f; __syncthreads();
    for (int s = 128; s > 0; s >>= 1) { if (tid < s) s_red[tid] += s_red[tid + s]; __syncthreads(); }
    float mu = s_red[0] * (1.f / 128.f);
    __syncthreads();
    float dv = (tid < 128) ? (g - mu) : 0.f;
    s_red[tid] = dv * dv; __syncthreads();
    for (int s = 128; s > 0; s >>= 1) { if (tid < s) s_red[tid] += s_red[tid + s]; __syncthreads(); }
    float var = s_red[0] * (1.f / 128.f);
    if (tid < 128) {
        float y = (g - mu) * rsqrtf(var + LN_EPS) * ln_w[tid] + ln_b[tid];
        h_out[(size_t)n * DIM + tid] = fmaxf(y, 0.f) + h_in[(size_t)n * DIM + tid];
    }
}

// ---------------------------------------------------------------------------
// Graph pooling: mean + max per graph (batch sorted -> binary search range)
// ---------------------------------------------------------------------------
__device__ int lower_bound_dev(const int* a, int n, int v) {
    int lo = 0, hi = n;
    while (lo < hi) { int mid = (lo + hi) >> 1; if (a[mid] < v) lo = mid + 1; else hi = mid; }
    return lo;
}

__global__ __launch_bounds__(128) void pool_kernel(const float* __restrict__ h,
                                                   const int* __restrict__ batch,
                                                   float* __restrict__ gmean,
                                                   float* __restrict__ gmax) {
    int g = blockIdx.x, d = threadIdx.x;
    int lo = lower_bound_dev(batch, N_NODES, g);
    int hi = lower_bound_dev(batch, N_NODES, g + 1);
    float s = 0.f, m = -1e30f;
    for (int i = lo; i < hi; i++) {
        float v = h[(size_t)i * DIM + d];
        s += v; m = fmaxf(m, v);
    }
    int cnt = hi - lo;
    gmean[g * DIM + d] = s / fmaxf((float)cnt, 1.f);
    gmax[g * DIM + d]  = (cnt > 0) ? m : 0.f;
}

// ---------------------------------------------------------------------------
// TDA MLP: relu(relu(tda@w1+b1)@w2+b2)   [256,30]->[256,64]->[256,64]
// ---------------------------------------------------------------------------
__global__ __launch_bounds__(64) void tda_kernel(const float* __restrict__ tda,
                                                 const float* __restrict__ w1, const float* __restrict__ b1,
                                                 const float* __restrict__ w2, const float* __restrict__ b2,
                                                 float* __restrict__ out) {
    __shared__ float tr[F_TDA];
    __shared__ float t1[64];
    int g = blockIdx.x, j = threadIdx.x;
    if (j < F_TDA) tr[j] = tda[g * F_TDA + j];
    __syncthreads();
    float acc = b1[j];
#pragma unroll
    for (int k = 0; k < F_TDA; k++) acc += tr[k] * w1[k * 64 + j];
    t1[j] = fmaxf(acc, 0.f);
    __syncthreads();
    float acc2 = b2[j];
#pragma unroll
    for (int k = 0; k < 64; k++) acc2 += t1[k] * w2[k * 64 + j];
    out[g * 64 + j] = fmaxf(acc2, 0.f);
}

// ---------------------------------------------------------------------------
// Trunk layer 1: relu([mean|max|tda] @ w_sh1 + b_sh1)  [256,320]->[256,256]
// ---------------------------------------------------------------------------
__global__ __launch_bounds__(256) void sh1_kernel(const float* __restrict__ gmean,
                                                  const float* __restrict__ gmax,
                                                  const float* __restrict__ tda_o,
                                                  const float* __restrict__ w, const float* __restrict__ b,
                                                  float* __restrict__ out) {
    __shared__ float c[320];
    int g = blockIdx.x, j = threadIdx.x;
    if (j < 128) c[j] = gmean[g * 128 + j];
    else         c[j] = gmax[g * 128 + (j - 128)];
    if (j < 64)  c[256 + j] = tda_o[g * 64 + j];
    __syncthreads();
    float acc = b[j];
    for (int k = 0; k < 320; k++) acc += c[k] * w[k * 256 + j];
    out[g * 256 + j] = fmaxf(acc, 0.f);
}

// Trunk layer 2: relu(sh1 @ w_sh2 + b_sh2)  [256,256]->[256,128]
__global__ __launch_bounds__(128) void sh2_kernel(const float* __restrict__ in,
                                                  const float* __restrict__ w, const float* __restrict__ b,
                                                  float* __restrict__ out) {
    __shared__ float c[256];
    int g = blockIdx.x, j = threadIdx.x;
    c[j] = in[g * 256 + j];
    c[j + 128] = in[g * 256 + j + 128];
    __syncthreads();
    float acc = b[j];
    for (int k = 0; k < 256; k++) acc += c[k] * w[k * 128 + j];
    out[g * 128 + j] = fmaxf(acc, 0.f);
}

// Task heads: out[t,g] = relu(shared[g] @ w_h1[t] + b_h1[t]) @ w_h2[t] + b_h2[t]
__global__ __launch_bounds__(64) void heads_kernel(const float* __restrict__ shared_in,
                                                   const float* __restrict__ w_h1, const float* __restrict__ b_h1,
                                                   const float* __restrict__ w_h2, const float* __restrict__ b_h2,
                                                   float* __restrict__ out) {
    __shared__ float sh[128];
    int bx = blockIdx.x;
    int t = bx >> 8, g = bx & 255;
    int k = threadIdx.x;
    sh[k] = shared_in[g * 128 + k];
    sh[k + 64] = shared_in[g * 128 + k + 64];
    __syncthreads();
    const float* w1 = w_h1 + (size_t)t * 128 * 64;
    float acc = b_h1[t * 64 + k];
#pragma unroll 16
    for (int d = 0; d < 128; d++) acc += sh[d] * w1[d * 64 + k];
    float p = fmaxf(acc, 0.f) * w_h2[t * 64 + k];
#pragma unroll
    for (int off = 32; off; off >>= 1) p += __shfl_xor(p, off);
    if (k == 0) out[t * 256 + g] = p + b_h2[t];
}

// ---------------------------------------------------------------------------
extern "C" void kernel_launch(void* const* d_in, const int* in_sizes, int n_in,
                              void* d_out, int out_size, void* d_ws, size_t ws_size,
                              hipStream_t stream) {
    const float* x        = (const float*)d_in[0];
    const int*   edge_idx = (const int*)  d_in[1];
    const int*   batch    = (const int*)  d_in[2];
    const float* tda      = (const float*)d_in[3];
    const float* w_in     = (const float*)d_in[4];
    const float* b_in     = (const float*)d_in[5];
    const float* w_gat    = (const float*)d_in[6];
    const float* a_src    = (const float*)d_in[7];
    const float* a_dst    = (const float*)d_in[8];
    const float* b_gat    = (const float*)d_in[9];
    const float* ln_w     = (const float*)d_in[10];
    const float* ln_b     = (const float*)d_in[11];
    const float* w_tda1   = (const float*)d_in[12];
    const float* b_tda1   = (const float*)d_in[13];
    const float* w_tda2   = (const float*)d_in[14];
    const float* b_tda2   = (const float*)d_in[15];
    const float* w_sh1    = (const float*)d_in[16];
    const float* b_sh1    = (const float*)d_in[17];
    const float* w_sh2    = (const float*)d_in[18];
    const float* b_sh2    = (const float*)d_in[19];
    const float* w_h1     = (const float*)d_in[20];
    const float* b_h1     = (const float*)d_in[21];
    const float* w_h2     = (const float*)d_in[22];
    const float* b_h2     = (const float*)d_in[23];
    float* out = (float*)d_out;

    // workspace carve-up (256B aligned)
    size_t off = 0;
    auto alloc = [&](size_t bytes) -> void* {
        void* p = (char*)d_ws + off;
        off += (bytes + 255) & ~(size_t)255;
        return p;
    };
    float* h_a    = (float*)alloc((size_t)N_NODES * DIM * 4);
    float* h_b    = (float*)alloc((size_t)N_NODES * DIM * 4);
    float* hh     = (float*)alloc((size_t)N_NODES * NHEAD * DIM * 4);
    float* al_s   = (float*)alloc((size_t)N_NODES * NHEAD * 4);
    float* al_d   = (float*)alloc((size_t)N_NODES * NHEAD * 4);
    int*   counts = (int*)  alloc((size_t)N_NODES * 4);
    int*   cursor = (int*)  alloc((size_t)N_NODES * 4);
    int*   rowptr = (int*)  alloc((size_t)(N_NODES + 1) * 4);
    int*   csrsrc = (int*)  alloc((size_t)E_TOTAL * 4);
    float* gmean  = (float*)alloc((size_t)N_GRAPHS * DIM * 4);
    float* gmax   = (float*)alloc((size_t)N_GRAPHS * DIM * 4);
    float* tda_o  = (float*)alloc((size_t)N_GRAPHS * 64 * 4);
    float* sh1_o  = (float*)alloc((size_t)N_GRAPHS * 256 * 4);
    float* sh2_o  = (float*)alloc((size_t)N_GRAPHS * 128 * 4);

    // CSR build
    hipMemsetAsync(counts, 0, (size_t)N_NODES * 4, stream);
    int eb = (E_TOTAL + 255) / 256;
    count_kernel<<<eb, 256, 0, stream>>>(edge_idx, counts);
    scan_kernel<<<1, 1024, 0, stream>>>(counts, rowptr, cursor, N_NODES);
    scatter_kernel<<<eb, 256, 0, stream>>>(edge_idx, cursor, csrsrc);

    // input projection
    proj_in_kernel<<<N_NODES, 128, 0, stream>>>(x, w_in, b_in, h_a);

    float* h_cur = h_a;
    float* h_nxt = h_b;
    for (int l = 0; l < NLAYER; l++) {
        gemm_hh_kernel<<<dim3(8, (N_NODES + 63) / 64), 256, 0, stream>>>(
            h_cur, w_gat + (size_t)l * 128 * 512, hh, N_NODES);
        alpha_kernel<<<N_NODES, 256, 0, stream>>>(
            hh, a_src + (size_t)l * NHEAD * DIM, a_dst + (size_t)l * NHEAD * DIM, al_s, al_d);
        gat_aggregate_kernel<<<N_NODES, 256, 0, stream>>>(
            hh, al_s, al_d, rowptr, csrsrc, h_cur,
            b_gat + (size_t)l * DIM, ln_w + (size_t)l * DIM, ln_b + (size_t)l * DIM, h_nxt);
        float* t = h_cur; h_cur = h_nxt; h_nxt = t;
    }

    // pooling + MLPs
    pool_kernel<<<N_GRAPHS, 128, 0, stream>>>(h_cur, batch, gmean, gmax);
    tda_kernel<<<N_GRAPHS, 64, 0, stream>>>(tda, w_tda1, b_tda1, w_tda2, b_tda2, tda_o);
    sh1_kernel<<<N_GRAPHS, 256, 0, stream>>>(gmean, gmax, tda_o, w_sh1, b_sh1, sh1_o);
    sh2_kernel<<<N_GRAPHS, 128, 0, stream>>>(sh1_o, w_sh2, b_sh2, sh2_o);
    heads_kernel<<<NTASK * N_GRAPHS, 64, 0, stream>>>(sh2_o, w_h1, b_h1, w_h2, b_h2, out);
}

// Round 2
// 545.033 us; speedup vs baseline: 1.3309x; 1.3309x over previous
//
#include <hip/hip_runtime.h>
#include <hip/hip_bf16.h>
#include <cstdint>
#include <cstddef>

// Problem constants (match reference)
#define N_NODES  20000
#define N_EDGES  320000
#define E_TOTAL  (N_EDGES + N_NODES)   // with self loops = 340000
#define N_GRAPHS 256
#define F_NODE   11
#define F_TDA    30
#define DIM      128
#define NHEAD    4
#define NLAYER   3
#define NTASK    6
#define NEG_SLOPE 0.2f
#define LN_EPS   1e-5f

typedef short bf16x8 __attribute__((ext_vector_type(8)));
typedef float f32x4  __attribute__((ext_vector_type(4)));

// f32 -> bf16 (round-to-nearest-even), returned as raw bits
__device__ inline unsigned short f2b(float f) {
    unsigned int u = __builtin_bit_cast(unsigned int, f);
    u += 0x7fffu + ((u >> 16) & 1u);
    return (unsigned short)(u >> 16);
}
__device__ inline float b2f(unsigned short b) {
    unsigned int u = ((unsigned int)b) << 16;
    return __builtin_bit_cast(float, u);
}

// ---------------------------------------------------------------------------
// CSR construction (dst-grouped) — rebuilt every call (no static state)
// ---------------------------------------------------------------------------
__global__ void count_kernel(const int* __restrict__ edge_index, int* __restrict__ counts) {
    int e = blockIdx.x * 256 + threadIdx.x;
    if (e >= E_TOTAL) return;
    int d = (e < N_EDGES) ? edge_index[N_EDGES + e] : (e - N_EDGES);
    atomicAdd(&counts[d], 1);
}

__global__ __launch_bounds__(1024) void scan_kernel(const int* __restrict__ counts,
                                                    int* __restrict__ row_ptr,
                                                    int* __restrict__ cursor, int n) {
    __shared__ int wsum[16];
    __shared__ int carry_s;
    int tid = threadIdx.x;
    int wave = tid >> 6, lane = tid & 63;
    if (tid == 0) carry_s = 0;
    __syncthreads();
    for (int base = 0; base < n; base += 1024) {
        int i = base + tid;
        int v = (i < n) ? counts[i] : 0;
        int x = v;
#pragma unroll
        for (int off = 1; off < 64; off <<= 1) {
            int y = __shfl_up(x, off);
            if (lane >= off) x += y;
        }
        if (lane == 63) wsum[wave] = x;
        __syncthreads();
        if (wave == 0 && lane < 16) {
            int w = wsum[lane];
#pragma unroll
            for (int off = 1; off < 16; off <<= 1) {
                int y = __shfl_up(w, off);
                if (lane >= off) w += y;
            }
            wsum[lane] = w;
        }
        __syncthreads();
        int woff = (wave == 0) ? 0 : wsum[wave - 1];
        int incl = carry_s + woff + x;
        if (i < n) { int r = incl - v; row_ptr[i] = r; cursor[i] = r; }
        __syncthreads();
        if (tid == 1023) carry_s = incl;
        __syncthreads();
    }
    if (tid == 0) row_ptr[n] = carry_s;
}

__global__ void scatter_kernel(const int* __restrict__ edge_index, int* __restrict__ cursor,
                               int* __restrict__ csr_src) {
    int e = blockIdx.x * 256 + threadIdx.x;
    if (e >= E_TOTAL) return;
    int s, d;
    if (e < N_EDGES) { s = edge_index[e]; d = edge_index[N_EDGES + e]; }
    else             { s = e - N_EDGES;   d = s; }
    int pos = atomicAdd(&cursor[d], 1);
    csr_src[pos] = s;
}

// ---------------------------------------------------------------------------
// Input projection: h = relu(x @ w_in + b_in); writes f32 + bf16 copies
// ---------------------------------------------------------------------------
__global__ __launch_bounds__(128) void proj_in_kernel(const float* __restrict__ x,
                                                      const float* __restrict__ w,
                                                      const float* __restrict__ b,
                                                      float* __restrict__ h,
                                                      unsigned short* __restrict__ h_bf) {
    __shared__ float xr[F_NODE];
    int n = blockIdx.x, d = threadIdx.x;
    if (d < F_NODE) xr[d] = x[n * F_NODE + d];
    __syncthreads();
    float acc = b[d];
#pragma unroll
    for (int k = 0; k < F_NODE; k++) acc += xr[k] * w[k * DIM + d];
    float v = fmaxf(acc, 0.f);
    h[(size_t)n * DIM + d] = v;
    h_bf[(size_t)n * DIM + d] = f2b(v);
}

// ---------------------------------------------------------------------------
// Weight transpose+cast: w_gat [L][128][512] f32 -> Wt [L][512][128] bf16
// ---------------------------------------------------------------------------
__global__ __launch_bounds__(256) void wtrans_kernel(const float* __restrict__ w_gat,
                                                     unsigned short* __restrict__ wt) {
    int i = blockIdx.x * 256 + threadIdx.x;   // over L*512*128
    if (i >= NLAYER * 512 * 128) return;
    int k = i & 127;
    int n = (i >> 7) & 511;
    int l = i >> 16;
    wt[i] = f2b(w_gat[(size_t)l * 65536 + (size_t)k * 512 + n]);
}

// ---------------------------------------------------------------------------
// MFMA GEMM: hh = h_bf @ W   [M,128]bf16 @ [128,512]bf16 -> [M,512] bf16
// 64x64 tile, 4 waves, 16x16x32 MFMA, K=128 in 4 steps.
// ---------------------------------------------------------------------------
__global__ __launch_bounds__(256) void gemm_mfma_kernel(const unsigned short* __restrict__ A,
                                                        const unsigned short* __restrict__ Bt,
                                                        unsigned short* __restrict__ C, int M) {
    // row pitch 136 bf16 = 272 B (16B-aligned, +8 pad kills b128 bank conflicts)
    __shared__ __align__(16) unsigned short As[64 * 136];
    __shared__ __align__(16) unsigned short Bs[64 * 136];
    int tid = threadIdx.x;
    int m0 = blockIdx.y << 6, n0 = blockIdx.x << 6;

    // stage A (64 rows x 128 k) and B (64 n-rows x 128 k), 16B per thread x4
    const uint4 zero4 = make_uint4(0, 0, 0, 0);
#pragma unroll
    for (int p = 0; p < 4; p++) {
        int i = p * 256 + tid;          // 1024 = 64 rows * 16 groups
        int row = i >> 4, kg = i & 15;
        int arow = m0 + row;
        uint4 av = (arow < M) ? *(const uint4*)(A + (size_t)arow * 128 + kg * 8) : zero4;
        *(uint4*)&As[row * 136 + kg * 8] = av;
        uint4 bv = *(const uint4*)(Bt + (size_t)(n0 + row) * 128 + kg * 8);
        *(uint4*)&Bs[row * 136 + kg * 8] = bv;
    }
    __syncthreads();

    int wave = tid >> 6, lane = tid & 63;
    int lr = lane & 15, lg = lane >> 4;
    f32x4 acc[4] = {};
#pragma unroll
    for (int ks = 0; ks < 4; ks++) {
        bf16x8 af = *(const bf16x8*)&As[(wave * 16 + lr) * 136 + ks * 32 + lg * 8];
#pragma unroll
        for (int nt = 0; nt < 4; nt++) {
            bf16x8 bf_ = *(const bf16x8*)&Bs[(nt * 16 + lr) * 136 + ks * 32 + lg * 8];
            acc[nt] = __builtin_amdgcn_mfma_f32_16x16x32_bf16(af, bf_, acc[nt], 0, 0, 0);
        }
    }
    // store: row = m0 + wave*16 + lg*4 + r ; col = n0 + nt*16 + lr
#pragma unroll
    for (int nt = 0; nt < 4; nt++) {
#pragma unroll
        for (int r = 0; r < 4; r++) {
            int row = m0 + wave * 16 + lg * 4 + r;
            if (row < M) C[(size_t)row * 512 + n0 + nt * 16 + lr] = f2b(acc[nt][r]);
        }
    }
}

// ---------------------------------------------------------------------------
// alpha_s[n,h] = <hh[n,h,:], a_src[h,:]> ; alpha_d likewise. 1 wave per (n,h).
// ---------------------------------------------------------------------------
__global__ __launch_bounds__(256) void alpha_kernel(const unsigned short* __restrict__ hh,
                                                    const float* __restrict__ a_s,
                                                    const float* __restrict__ a_d,
                                                    float* __restrict__ out_s,
                                                    float* __restrict__ out_d) {
    int n = blockIdx.x;
    int h = threadIdx.x >> 6;
    int lane = threadIdx.x & 63;
    unsigned int u = *(const unsigned int*)(hh + (size_t)n * 512 + h * 128 + lane * 2);
    float lo = __builtin_bit_cast(float, u << 16);
    float hi = __builtin_bit_cast(float, u & 0xffff0000u);
    float ss = lo * a_s[h * 128 + lane * 2] + hi * a_s[h * 128 + lane * 2 + 1];
    float sd = lo * a_d[h * 128 + lane * 2] + hi * a_d[h * 128 + lane * 2 + 1];
#pragma unroll
    for (int off = 32; off; off >>= 1) { ss += __shfl_xor(ss, off); sd += __shfl_xor(sd, off); }
    if (lane == 0) { out_s[n * 4 + h] = ss; out_d[n * 4 + h] = sd; }
}

// ---------------------------------------------------------------------------
// Per-dst-node GAT tail: edge softmax + bf16 message aggregation + head mean
// + bias + LayerNorm + ReLU + residual. Writes f32 + bf16 h_out.
// ---------------------------------------------------------------------------
__global__ __launch_bounds__(256) void gat_aggregate_kernel(
    const unsigned short* __restrict__ hh, const float* __restrict__ al_s,
    const float* __restrict__ al_d, const int* __restrict__ row_ptr,
    const int* __restrict__ csr_src, const float* __restrict__ h_in,
    const float* __restrict__ b_gat, const float* __restrict__ ln_w,
    const float* __restrict__ ln_b, float* __restrict__ h_out,
    unsigned short* __restrict__ h_out_bf) {
    __shared__ float s_red[512];
    __shared__ float m_h[4], l_h[4];
    __shared__ float w_chunk[64][4];
    __shared__ int   src_chunk[64];

    int n = blockIdx.x;
    int tid = threadIdx.x;
    int begin = row_ptr[n], end = row_ptr[n + 1];
    int deg = end - begin;             // >= 1 (self loop)
    int h4 = tid & 3;
    float ad = al_d[n * 4 + h4];

    // phase 1: per-head max of leaky_relu(alpha_s[src]+alpha_d[n])
    float lm = -1e30f;
    for (int i = tid; i < deg * 4; i += 256) {
        int s = csr_src[begin + (i >> 2)];
        float v = al_s[s * 4 + h4] + ad;
        v = (v > 0.f) ? v : NEG_SLOPE * v;
        lm = fmaxf(lm, v);
    }
    s_red[tid] = lm; __syncthreads();
    for (int s = 128; s >= 4; s >>= 1) { if (tid < s) s_red[tid] = fmaxf(s_red[tid], s_red[tid + s]); __syncthreads(); }
    if (tid < 4) m_h[tid] = s_red[tid];
    __syncthreads();

    // phase 2: per-head sum of exp
    float mh = m_h[h4];
    float ls = 0.f;
    for (int i = tid; i < deg * 4; i += 256) {
        int s = csr_src[begin + (i >> 2)];
        float v = al_s[s * 4 + h4] + ad;
        v = (v > 0.f) ? v : NEG_SLOPE * v;
        ls += __expf(v - mh);
    }
    s_red[tid] = ls; __syncthreads();
    for (int s = 128; s >= 4; s >>= 1) { if (tid < s) s_red[tid] += s_red[tid + s]; __syncthreads(); }
    if (tid < 4) l_h[tid] = s_red[tid];
    __syncthreads();

    // phase 3: weighted aggregation; thread owns features 2*tid, 2*tid+1 of [H*D]
    float inv_l = 1.f / l_h[h4];
    int hA = tid >> 6;                 // head of features 2*tid, 2*tid+1
    float accx = 0.f, accy = 0.f;
    for (int cb = 0; cb < deg; cb += 64) {
        int ce = min(64, deg - cb);
        if (tid < ce * 4) {
            int e = tid >> 2;
            int s = csr_src[begin + cb + e];
            if (h4 == 0) src_chunk[e] = s;
            float v = al_s[s * 4 + h4] + ad;
            v = (v > 0.f) ? v : NEG_SLOPE * v;
            w_chunk[e][h4] = __expf(v - mh) * inv_l;
        }
        __syncthreads();
        for (int e = 0; e < ce; e++) {
            int s = src_chunk[e];
            float w = w_chunk[e][hA];
            unsigned int u = *(const unsigned int*)(hh + (size_t)s * 512 + 2 * tid);
            accx += w * __builtin_bit_cast(float, u << 16);
            accy += w * __builtin_bit_cast(float, u & 0xffff0000u);
        }
        __syncthreads();
    }

    // head mean + bias
    s_red[2 * tid] = accx;
    s_red[2 * tid + 1] = accy;
    __syncthreads();
    float g = 0.f;
    if (tid < 128)
        g = (s_red[tid] + s_red[128 + tid] + s_red[256 + tid] + s_red[384 + tid]) * 0.25f + b_gat[tid];
    __syncthreads();

    // LayerNorm over 128 features (reuse s_red[0..255])
    s_red[tid] = (tid < 128) ? g : 0.f; __syncthreads();
    for (int s = 128; s > 0; s >>= 1) { if (tid < s) s_red[tid] += s_red[tid + s]; __syncthreads(); }
    float mu = s_red[0] * (1.f / 128.f);
    __syncthreads();
    float dv = (tid < 128) ? (g - mu) : 0.f;
    s_red[tid] = dv * dv; __syncthreads();
    for (int s = 128; s > 0; s >>= 1) { if (tid < s) s_red[tid] += s_red[tid + s]; __syncthreads(); }
    float var = s_red[0] * (1.f / 128.f);
    if (tid < 128) {
        float y = (g - mu) * rsqrtf(var + LN_EPS) * ln_w[tid] + ln_b[tid];
        float o = fmaxf(y, 0.f) + h_in[(size_t)n * DIM + tid];
        h_out[(size_t)n * DIM + tid] = o;
        h_out_bf[(size_t)n * DIM + tid] = f2b(o);
    }
}

// ---------------------------------------------------------------------------
// Graph pooling: mean + max per graph (batch sorted -> binary search range)
// ---------------------------------------------------------------------------
__device__ int lower_bound_dev(const int* a, int n, int v) {
    int lo = 0, hi = n;
    while (lo < hi) { int mid = (lo + hi) >> 1; if (a[mid] < v) lo = mid + 1; else hi = mid; }
    return lo;
}

__global__ __launch_bounds__(128) void pool_kernel(const float* __restrict__ h,
                                                   const int* __restrict__ batch,
                                                   float* __restrict__ gmean,
                                                   float* __restrict__ gmax) {
    int g = blockIdx.x, d = threadIdx.x;
    int lo = lower_bound_dev(batch, N_NODES, g);
    int hi = lower_bound_dev(batch, N_NODES, g + 1);
    float s = 0.f, m = -1e30f;
    for (int i = lo; i < hi; i++) {
        float v = h[(size_t)i * DIM + d];
        s += v; m = fmaxf(m, v);
    }
    int cnt = hi - lo;
    gmean[g * DIM + d] = s / fmaxf((float)cnt, 1.f);
    gmax[g * DIM + d]  = (cnt > 0) ? m : 0.f;
}

// ---------------------------------------------------------------------------
// TDA MLP: relu(relu(tda@w1+b1)@w2+b2)
// ---------------------------------------------------------------------------
__global__ __launch_bounds__(64) void tda_kernel(const float* __restrict__ tda,
                                                 const float* __restrict__ w1, const float* __restrict__ b1,
                                                 const float* __restrict__ w2, const float* __restrict__ b2,
                                                 float* __restrict__ out) {
    __shared__ float tr[F_TDA];
    __shared__ float t1[64];
    int g = blockIdx.x, j = threadIdx.x;
    if (j < F_TDA) tr[j] = tda[g * F_TDA + j];
    __syncthreads();
    float acc = b1[j];
#pragma unroll
    for (int k = 0; k < F_TDA; k++) acc += tr[k] * w1[k * 64 + j];
    t1[j] = fmaxf(acc, 0.f);
    __syncthreads();
    float acc2 = b2[j];
#pragma unroll
    for (int k = 0; k < 64; k++) acc2 += t1[k] * w2[k * 64 + j];
    out[g * 64 + j] = fmaxf(acc2, 0.f);
}

__global__ __launch_bounds__(256) void sh1_kernel(const float* __restrict__ gmean,
                                                  const float* __restrict__ gmax,
                                                  const float* __restrict__ tda_o,
                                                  const float* __restrict__ w, const float* __restrict__ b,
                                                  float* __restrict__ out) {
    __shared__ float c[320];
    int g = blockIdx.x, j = threadIdx.x;
    if (j < 128) c[j] = gmean[g * 128 + j];
    else         c[j] = gmax[g * 128 + (j - 128)];
    if (j < 64)  c[256 + j] = tda_o[g * 64 + j];
    __syncthreads();
    float acc = b[j];
    for (int k = 0; k < 320; k++) acc += c[k] * w[k * 256 + j];
    out[g * 256 + j] = fmaxf(acc, 0.f);
}

__global__ __launch_bounds__(128) void sh2_kernel(const float* __restrict__ in,
                                                  const float* __restrict__ w, const float* __restrict__ b,
                                                  float* __restrict__ out) {
    __shared__ float c[256];
    int g = blockIdx.x, j = threadIdx.x;
    c[j] = in[g * 256 + j];
    c[j + 128] = in[g * 256 + j + 128];
    __syncthreads();
    float acc = b[j];
    for (int k = 0; k < 256; k++) acc += c[k] * w[k * 128 + j];
    out[g * 128 + j] = fmaxf(acc, 0.f);
}

__global__ __launch_bounds__(64) void heads_kernel(const float* __restrict__ shared_in,
                                                   const float* __restrict__ w_h1, const float* __restrict__ b_h1,
                                                   const float* __restrict__ w_h2, const float* __restrict__ b_h2,
                                                   float* __restrict__ out) {
    __shared__ float sh[128];
    int bx = blockIdx.x;
    int t = bx >> 8, g = bx & 255;
    int k = threadIdx.x;
    sh[k] = shared_in[g * 128 + k];
    sh[k + 64] = shared_in[g * 128 + k + 64];
    __syncthreads();
    const float* w1 = w_h1 + (size_t)t * 128 * 64;
    float acc = b_h1[t * 64 + k];
#pragma unroll 16
    for (int d = 0; d < 128; d++) acc += sh[d] * w1[d * 64 + k];
    float p = fmaxf(acc, 0.f) * w_h2[t * 64 + k];
#pragma unroll
    for (int off = 32; off; off >>= 1) p += __shfl_xor(p, off);
    if (k == 0) out[t * 256 + g] = p + b_h2[t];
}

// ---------------------------------------------------------------------------
extern "C" void kernel_launch(void* const* d_in, const int* in_sizes, int n_in,
                              void* d_out, int out_size, void* d_ws, size_t ws_size,
                              hipStream_t stream) {
    const float* x        = (const float*)d_in[0];
    const int*   edge_idx = (const int*)  d_in[1];
    const int*   batch    = (const int*)  d_in[2];
    const float* tda      = (const float*)d_in[3];
    const float* w_in     = (const float*)d_in[4];
    const float* b_in     = (const float*)d_in[5];
    const float* w_gat    = (const float*)d_in[6];
    const float* a_src    = (const float*)d_in[7];
    const float* a_dst    = (const float*)d_in[8];
    const float* b_gat    = (const float*)d_in[9];
    const float* ln_w     = (const float*)d_in[10];
    const float* ln_b     = (const float*)d_in[11];
    const float* w_tda1   = (const float*)d_in[12];
    const float* b_tda1   = (const float*)d_in[13];
    const float* w_tda2   = (const float*)d_in[14];
    const float* b_tda2   = (const float*)d_in[15];
    const float* w_sh1    = (const float*)d_in[16];
    const float* b_sh1    = (const float*)d_in[17];
    const float* w_sh2    = (const float*)d_in[18];
    const float* b_sh2    = (const float*)d_in[19];
    const float* w_h1     = (const float*)d_in[20];
    const float* b_h1     = (const float*)d_in[21];
    const float* w_h2     = (const float*)d_in[22];
    const float* b_h2     = (const float*)d_in[23];
    float* out = (float*)d_out;

    // workspace carve-up (256B aligned)
    size_t off = 0;
    auto alloc = [&](size_t bytes) -> void* {
        void* p = (char*)d_ws + off;
        off += (bytes + 255) & ~(size_t)255;
        return p;
    };
    float*          h_a    = (float*)alloc((size_t)N_NODES * DIM * 4);
    float*          h_b    = (float*)alloc((size_t)N_NODES * DIM * 4);
    unsigned short* hb_a   = (unsigned short*)alloc((size_t)N_NODES * DIM * 2);
    unsigned short* hb_b   = (unsigned short*)alloc((size_t)N_NODES * DIM * 2);
    unsigned short* hh     = (unsigned short*)alloc((size_t)N_NODES * NHEAD * DIM * 2);
    unsigned short* wt     = (unsigned short*)alloc((size_t)NLAYER * 512 * 128 * 2);
    float*          al_s   = (float*)alloc((size_t)N_NODES * NHEAD * 4);
    float*          al_d   = (float*)alloc((size_t)N_NODES * NHEAD * 4);
    int*            counts = (int*)  alloc((size_t)N_NODES * 4);
    int*            cursor = (int*)  alloc((size_t)N_NODES * 4);
    int*            rowptr = (int*)  alloc((size_t)(N_NODES + 1) * 4);
    int*            csrsrc = (int*)  alloc((size_t)E_TOTAL * 4);
    float*          gmean  = (float*)alloc((size_t)N_GRAPHS * DIM * 4);
    float*          gmax   = (float*)alloc((size_t)N_GRAPHS * DIM * 4);
    float*          tda_o  = (float*)alloc((size_t)N_GRAPHS * 64 * 4);
    float*          sh1_o  = (float*)alloc((size_t)N_GRAPHS * 256 * 4);
    float*          sh2_o  = (float*)alloc((size_t)N_GRAPHS * 128 * 4);

    // CSR build
    hipMemsetAsync(counts, 0, (size_t)N_NODES * 4, stream);
    int eb = (E_TOTAL + 255) / 256;
    count_kernel<<<eb, 256, 0, stream>>>(edge_idx, counts);
    scan_kernel<<<1, 1024, 0, stream>>>(counts, rowptr, cursor, N_NODES);
    scatter_kernel<<<eb, 256, 0, stream>>>(edge_idx, cursor, csrsrc);

    // weight transpose (all layers), input projection
    wtrans_kernel<<<(NLAYER * 512 * 128 + 255) / 256, 256, 0, stream>>>(w_gat, wt);
    proj_in_kernel<<<N_NODES, 128, 0, stream>>>(x, w_in, b_in, h_a, hb_a);

    float* h_cur = h_a;  unsigned short* hb_cur = hb_a;
    float* h_nxt = h_b;  unsigned short* hb_nxt = hb_b;
    for (int l = 0; l < NLAYER; l++) {
        gemm_mfma_kernel<<<dim3(8, (N_NODES + 63) / 64), 256, 0, stream>>>(
            hb_cur, wt + (size_t)l * 512 * 128, hh, N_NODES);
        alpha_kernel<<<N_NODES, 256, 0, stream>>>(
            hh, a_src + (size_t)l * NHEAD * DIM, a_dst + (size_t)l * NHEAD * DIM, al_s, al_d);
        gat_aggregate_kernel<<<N_NODES, 256, 0, stream>>>(
            hh, al_s, al_d, rowptr, csrsrc, h_cur,
            b_gat + (size_t)l * DIM, ln_w + (size_t)l * DIM, ln_b + (size_t)l * DIM,
            h_nxt, hb_nxt);
        float* t = h_cur; h_cur = h_nxt; h_nxt = t;
        unsigned short* tb = hb_cur; hb_cur = hb_nxt; hb_nxt = tb;
    }

    // pooling + MLPs
    pool_kernel<<<N_GRAPHS, 128, 0, stream>>>(h_cur, batch, gmean, gmax);
    tda_kernel<<<N_GRAPHS, 64, 0, stream>>>(tda, w_tda1, b_tda1, w_tda2, b_tda2, tda_o);
    sh1_kernel<<<N_GRAPHS, 256, 0, stream>>>(gmean, gmax, tda_o, w_sh1, b_sh1, sh1_o);
    sh2_kernel<<<N_GRAPHS, 128, 0, stream>>>(sh1_o, w_sh2, b_sh2, sh2_o);
    heads_kernel<<<NTASK * N_GRAPHS, 64, 0, stream>>>(sh2_o, w_h1, b_h1, w_h2, b_h2, out);
}

// Round 3
// 504.768 us; speedup vs baseline: 1.4371x; 1.0798x over previous
//
#include <hip/hip_runtime.h>
#include <hip/hip_bf16.h>
#include <cstdint>
#include <cstddef>

// Problem constants (match reference)
#define N_NODES  20000
#define N_EDGES  320000
#define E_TOTAL  (N_EDGES + N_NODES)   // with self loops = 340000
#define N_GRAPHS 256
#define F_NODE   11
#define F_TDA    30
#define DIM      128
#define NHEAD    4
#define NLAYER   3
#define NTASK    6
#define NEG_SLOPE 0.2f
#define LN_EPS   1e-5f

typedef short bf16x8 __attribute__((ext_vector_type(8)));
typedef float f32x4  __attribute__((ext_vector_type(4)));

// f32 -> bf16 (round-to-nearest-even), returned as raw bits
__device__ inline unsigned short f2b(float f) {
    unsigned int u = __builtin_bit_cast(unsigned int, f);
    u += 0x7fffu + ((u >> 16) & 1u);
    return (unsigned short)(u >> 16);
}

// ---------------------------------------------------------------------------
// CSR construction (dst-grouped) — rebuilt every call (no static state)
// ---------------------------------------------------------------------------
__global__ void count_kernel(const int* __restrict__ edge_index, int* __restrict__ counts) {
    int e = blockIdx.x * 256 + threadIdx.x;
    if (e >= E_TOTAL) return;
    int d = (e < N_EDGES) ? edge_index[N_EDGES + e] : (e - N_EDGES);
    atomicAdd(&counts[d], 1);
}

__global__ __launch_bounds__(1024) void scan_kernel(const int* __restrict__ counts,
                                                    int* __restrict__ row_ptr,
                                                    int* __restrict__ cursor, int n) {
    __shared__ int wsum[16];
    __shared__ int carry_s;
    int tid = threadIdx.x;
    int wave = tid >> 6, lane = tid & 63;
    if (tid == 0) carry_s = 0;
    __syncthreads();
    for (int base = 0; base < n; base += 1024) {
        int i = base + tid;
        int v = (i < n) ? counts[i] : 0;
        int x = v;
#pragma unroll
        for (int off = 1; off < 64; off <<= 1) {
            int y = __shfl_up(x, off);
            if (lane >= off) x += y;
        }
        if (lane == 63) wsum[wave] = x;
        __syncthreads();
        if (wave == 0 && lane < 16) {
            int w = wsum[lane];
#pragma unroll
            for (int off = 1; off < 16; off <<= 1) {
                int y = __shfl_up(w, off);
                if (lane >= off) w += y;
            }
            wsum[lane] = w;
        }
        __syncthreads();
        int woff = (wave == 0) ? 0 : wsum[wave - 1];
        int incl = carry_s + woff + x;
        if (i < n) { int r = incl - v; row_ptr[i] = r; cursor[i] = r; }
        __syncthreads();
        if (tid == 1023) carry_s = incl;
        __syncthreads();
    }
    if (tid == 0) row_ptr[n] = carry_s;
}

__global__ void scatter_kernel(const int* __restrict__ edge_index, int* __restrict__ cursor,
                               int* __restrict__ csr_src) {
    int e = blockIdx.x * 256 + threadIdx.x;
    if (e >= E_TOTAL) return;
    int s, d;
    if (e < N_EDGES) { s = edge_index[e]; d = edge_index[N_EDGES + e]; }
    else             { s = e - N_EDGES;   d = s; }
    int pos = atomicAdd(&cursor[d], 1);
    csr_src[pos] = s;
}

// ---------------------------------------------------------------------------
// Input projection: h = relu(x @ w_in + b_in); writes f32 + bf16 copies
// ---------------------------------------------------------------------------
__global__ __launch_bounds__(128) void proj_in_kernel(const float* __restrict__ x,
                                                      const float* __restrict__ w,
                                                      const float* __restrict__ b,
                                                      float* __restrict__ h,
                                                      unsigned short* __restrict__ h_bf) {
    __shared__ float xr[F_NODE];
    int n = blockIdx.x, d = threadIdx.x;
    if (d < F_NODE) xr[d] = x[n * F_NODE + d];
    __syncthreads();
    float acc = b[d];
#pragma unroll
    for (int k = 0; k < F_NODE; k++) acc += xr[k] * w[k * DIM + d];
    float v = fmaxf(acc, 0.f);
    h[(size_t)n * DIM + d] = v;
    h_bf[(size_t)n * DIM + d] = f2b(v);
}

// ---------------------------------------------------------------------------
// Weight transpose+cast: w_gat [L][128][512] f32 -> Wt [L][512][128] bf16
// ---------------------------------------------------------------------------
__global__ __launch_bounds__(256) void wtrans_kernel(const float* __restrict__ w_gat,
                                                     unsigned short* __restrict__ wt) {
    int i = blockIdx.x * 256 + threadIdx.x;   // over L*512*128
    if (i >= NLAYER * 512 * 128) return;
    int k = i & 127;
    int n = (i >> 7) & 511;
    int l = i >> 16;
    wt[i] = f2b(w_gat[(size_t)l * 65536 + (size_t)k * 512 + n]);
}

// ---------------------------------------------------------------------------
// MFMA GEMM: hh = h_bf @ W   [M,128]bf16 @ [128,512]bf16 -> [M,512] bf16
// + fused alpha partials: al_s/al_d += (hh_tile) . a_src/a_dst  (atomicAdd)
// 64x64 tile, 4 waves, 16x16x32 MFMA, K=128 in 4 steps.
// ---------------------------------------------------------------------------
__global__ __launch_bounds__(256) void gemm_mfma_kernel(const unsigned short* __restrict__ A,
                                                        const unsigned short* __restrict__ Bt,
                                                        const float* __restrict__ a_sl,
                                                        const float* __restrict__ a_dl,
                                                        unsigned short* __restrict__ C,
                                                        float* __restrict__ al_s_out,
                                                        float* __restrict__ al_d_out, int M) {
    // row pitch 136 bf16 = 272 B (16B-aligned, +8 pad kills b128 bank conflicts)
    __shared__ __align__(16) unsigned short As[64 * 136];
    __shared__ __align__(16) unsigned short Bs[64 * 136];
    int tid = threadIdx.x;
    int m0 = blockIdx.y << 6, n0 = blockIdx.x << 6;

    const uint4 zero4 = make_uint4(0, 0, 0, 0);
#pragma unroll
    for (int p = 0; p < 4; p++) {
        int i = p * 256 + tid;          // 1024 = 64 rows * 16 k-groups
        int row = i >> 4, kg = i & 15;
        int arow = m0 + row;
        uint4 av = (arow < M) ? *(const uint4*)(A + (size_t)arow * 128 + kg * 8) : zero4;
        *(uint4*)&As[row * 136 + kg * 8] = av;
        uint4 bv = *(const uint4*)(Bt + (size_t)(n0 + row) * 128 + kg * 8);
        *(uint4*)&Bs[row * 136 + kg * 8] = bv;
    }
    __syncthreads();

    int wave = tid >> 6, lane = tid & 63;
    int lr = lane & 15, lg = lane >> 4;
    f32x4 acc[4] = {};
#pragma unroll
    for (int ks = 0; ks < 4; ks++) {
        bf16x8 af = *(const bf16x8*)&As[(wave * 16 + lr) * 136 + ks * 32 + lg * 8];
#pragma unroll
        for (int nt = 0; nt < 4; nt++) {
            bf16x8 bf_ = *(const bf16x8*)&Bs[(nt * 16 + lr) * 136 + ks * 32 + lg * 8];
            acc[nt] = __builtin_amdgcn_mfma_f32_16x16x32_bf16(af, bf_, acc[nt], 0, 0, 0);
        }
    }
    // store hh: row = m0 + wave*16 + lg*4 + r ; col = n0 + nt*16 + lr
#pragma unroll
    for (int nt = 0; nt < 4; nt++) {
#pragma unroll
        for (int r = 0; r < 4; r++) {
            int row = m0 + wave * 16 + lg * 4 + r;
            if (row < M) C[(size_t)row * 512 + n0 + nt * 16 + lr] = f2b(acc[nt][r]);
        }
    }

    // fused alpha partial dots for this block's 64 cols (all within head hblk)
    int hblk = n0 >> 7;
    int cbase = n0 & 127;
    float asv[4], adv[4];
#pragma unroll
    for (int nt = 0; nt < 4; nt++) {
        asv[nt] = a_sl[hblk * 128 + cbase + nt * 16 + lr];
        adv[nt] = a_dl[hblk * 128 + cbase + nt * 16 + lr];
    }
#pragma unroll
    for (int r = 0; r < 4; r++) {
        float ps = 0.f, pd = 0.f;
#pragma unroll
        for (int nt = 0; nt < 4; nt++) { ps += acc[nt][r] * asv[nt]; pd += acc[nt][r] * adv[nt]; }
#pragma unroll
        for (int off = 8; off; off >>= 1) { ps += __shfl_xor(ps, off); pd += __shfl_xor(pd, off); }
        int row = m0 + wave * 16 + lg * 4 + r;
        if (lr == 0 && row < M) {
            atomicAdd(&al_s_out[row * 4 + hblk], ps);
            atomicAdd(&al_d_out[row * 4 + hblk], pd);
        }
    }
}

// ---------------------------------------------------------------------------
// Per-dst-node GAT tail: online edge softmax + wave-per-edge bf16 aggregation
// + head mean + bias + LayerNorm + ReLU + residual. Writes f32 + bf16 h_out.
// ---------------------------------------------------------------------------
__global__ __launch_bounds__(256) void gat_aggregate_kernel(
    const unsigned short* __restrict__ hh, const float* __restrict__ al_s,
    const float* __restrict__ al_d, const int* __restrict__ row_ptr,
    const int* __restrict__ csr_src, const float* __restrict__ h_in,
    const float* __restrict__ b_gat, const float* __restrict__ ln_w,
    const float* __restrict__ ln_b, float* __restrict__ h_out,
    unsigned short* __restrict__ h_out_bf) {
    __shared__ float s_m[256], s_l[256];
    __shared__ float m_h[4], il_h[4];
    __shared__ float sm[4 * 512];
    __shared__ float wred[8];

    int n = blockIdx.x;
    int tid = threadIdx.x;
    int wave = tid >> 6, lane = tid & 63;
    int begin = row_ptr[n];
    int deg = row_ptr[n + 1] - begin;   // >= 1 (self loop)

    // ---- single-pass online softmax stats (m, l) per head ----
    int h4 = tid & 3;
    float ad4 = al_d[n * 4 + h4];
    float m = -1e30f, lsum = 0.f;
    for (int i = tid; i < deg * 4; i += 256) {
        int s = csr_src[begin + (i >> 2)];
        float v = al_s[s * 4 + h4] + ad4;
        v = (v > 0.f) ? v : NEG_SLOPE * v;
        if (v > m) { lsum = lsum * __expf(m - v) + 1.f; m = v; }
        else       { lsum += __expf(v - m); }
    }
    s_m[tid] = m; s_l[tid] = lsum;
    __syncthreads();
    for (int s = 128; s >= 4; s >>= 1) {
        if (tid < s) {
            float m1 = s_m[tid], l1 = s_l[tid];
            float m2 = s_m[tid + s], l2 = s_l[tid + s];
            float mx = fmaxf(m1, m2);
            s_m[tid] = mx;
            s_l[tid] = l1 * __expf(m1 - mx) + l2 * __expf(m2 - mx);
        }
        __syncthreads();
    }
    if (tid < 4) { m_h[tid] = s_m[tid]; il_h[tid] = 1.f / s_l[tid]; }
    __syncthreads();

    // ---- wave-per-edge aggregation: lane owns features lane*8..lane*8+7 ----
    int hl = lane >> 4;                 // head of this lane's features
    float mh = m_h[hl], il = il_h[hl];
    float adh = al_d[n * 4 + hl];
    float acc[8] = {};
    for (int e = wave; e < deg; e += 4) {
        int s = csr_src[begin + e];
        float v = al_s[s * 4 + hl] + adh;
        v = (v > 0.f) ? v : NEG_SLOPE * v;
        float w = __expf(v - mh) * il;
        uint4 u = *(const uint4*)(hh + (size_t)s * 512 + lane * 8);
        acc[0] += w * __builtin_bit_cast(float, u.x << 16);
        acc[1] += w * __builtin_bit_cast(float, u.x & 0xffff0000u);
        acc[2] += w * __builtin_bit_cast(float, u.y << 16);
        acc[3] += w * __builtin_bit_cast(float, u.y & 0xffff0000u);
        acc[4] += w * __builtin_bit_cast(float, u.z << 16);
        acc[5] += w * __builtin_bit_cast(float, u.z & 0xffff0000u);
        acc[6] += w * __builtin_bit_cast(float, u.w << 16);
        acc[7] += w * __builtin_bit_cast(float, u.w & 0xffff0000u);
    }
#pragma unroll
    for (int j = 0; j < 8; j++) sm[wave * 512 + lane * 8 + j] = acc[j];
    __syncthreads();

    // ---- cross-wave + head-mean + bias ----
    float g = 0.f;
    if (tid < 128) {
#pragma unroll
        for (int w = 0; w < 4; w++)
#pragma unroll
            for (int h = 0; h < 4; h++) g += sm[w * 512 + h * 128 + tid];
        g = g * 0.25f + b_gat[tid];
    }
    // ---- LayerNorm over 128 (shuffle + tiny LDS) ----
    float sv = (tid < 128) ? g : 0.f;
#pragma unroll
    for (int off = 32; off; off >>= 1) sv += __shfl_xor(sv, off);
    if (lane == 0) wred[wave] = sv;
    __syncthreads();
    float mu = (wred[0] + wred[1] + wred[2] + wred[3]) * (1.f / 128.f);
    float dv = (tid < 128) ? (g - mu) : 0.f;
    float sv2 = dv * dv;
#pragma unroll
    for (int off = 32; off; off >>= 1) sv2 += __shfl_xor(sv2, off);
    if (lane == 0) wred[4 + wave] = sv2;
    __syncthreads();
    float var = (wred[4] + wred[5] + wred[6] + wred[7]) * (1.f / 128.f);
    if (tid < 128) {
        float y = (g - mu) * rsqrtf(var + LN_EPS) * ln_w[tid] + ln_b[tid];
        float o = fmaxf(y, 0.f) + h_in[(size_t)n * DIM + tid];
        h_out[(size_t)n * DIM + tid] = o;
        h_out_bf[(size_t)n * DIM + tid] = f2b(o);
    }
}

// ---------------------------------------------------------------------------
// Graph pooling: mean + max per graph (batch sorted -> binary search range)
// 512 threads: 4 node-slices x 128 features, LDS combine.
// ---------------------------------------------------------------------------
__device__ int lower_bound_dev(const int* a, int n, int v) {
    int lo = 0, hi = n;
    while (lo < hi) { int mid = (lo + hi) >> 1; if (a[mid] < v) lo = mid + 1; else hi = mid; }
    return lo;
}

__global__ __launch_bounds__(512) void pool_kernel(const float* __restrict__ h,
                                                   const int* __restrict__ batch,
                                                   float* __restrict__ gmean,
                                                   float* __restrict__ gmax) {
    __shared__ float ssum[4][128];
    __shared__ float smax[4][128];
    __shared__ int bounds[2];
    int g = blockIdx.x;
    int tid = threadIdx.x;
    if (tid < 2) bounds[tid] = lower_bound_dev(batch, N_NODES, g + tid);
    __syncthreads();
    int lo = bounds[0], hi = bounds[1];
    int q = tid >> 7, d = tid & 127;
    float s = 0.f, m = -1e30f;
    for (int i = lo + q; i < hi; i += 4) {
        float v = h[(size_t)i * DIM + d];
        s += v; m = fmaxf(m, v);
    }
    ssum[q][d] = s; smax[q][d] = m;
    __syncthreads();
    if (tid < 128) {
        float S = ssum[0][d] + ssum[1][d] + ssum[2][d] + ssum[3][d];
        float M = fmaxf(fmaxf(smax[0][d], smax[1][d]), fmaxf(smax[2][d], smax[3][d]));
        int cnt = hi - lo;
        gmean[g * DIM + d] = S / fmaxf((float)cnt, 1.f);
        gmax[g * DIM + d]  = (cnt > 0) ? M : 0.f;
    }
}

// ---------------------------------------------------------------------------
// TDA MLP + trunk + heads (tiny)
// ---------------------------------------------------------------------------
__global__ __launch_bounds__(64) void tda_kernel(const float* __restrict__ tda,
                                                 const float* __restrict__ w1, const float* __restrict__ b1,
                                                 const float* __restrict__ w2, const float* __restrict__ b2,
                                                 float* __restrict__ out) {
    __shared__ float tr[F_TDA];
    __shared__ float t1[64];
    int g = blockIdx.x, j = threadIdx.x;
    if (j < F_TDA) tr[j] = tda[g * F_TDA + j];
    __syncthreads();
    float acc = b1[j];
#pragma unroll
    for (int k = 0; k < F_TDA; k++) acc += tr[k] * w1[k * 64 + j];
    t1[j] = fmaxf(acc, 0.f);
    __syncthreads();
    float acc2 = b2[j];
#pragma unroll
    for (int k = 0; k < 64; k++) acc2 += t1[k] * w2[k * 64 + j];
    out[g * 64 + j] = fmaxf(acc2, 0.f);
}

__global__ __launch_bounds__(256) void sh1_kernel(const float* __restrict__ gmean,
                                                  const float* __restrict__ gmax,
                                                  const float* __restrict__ tda_o,
                                                  const float* __restrict__ w, const float* __restrict__ b,
                                                  float* __restrict__ out) {
    __shared__ float c[320];
    int g = blockIdx.x, j = threadIdx.x;
    if (j < 128) c[j] = gmean[g * 128 + j];
    else         c[j] = gmax[g * 128 + (j - 128)];
    if (j < 64)  c[256 + j] = tda_o[g * 64 + j];
    __syncthreads();
    float acc = b[j];
    for (int k = 0; k < 320; k++) acc += c[k] * w[k * 256 + j];
    out[g * 256 + j] = fmaxf(acc, 0.f);
}

__global__ __launch_bounds__(128) void sh2_kernel(const float* __restrict__ in,
                                                  const float* __restrict__ w, const float* __restrict__ b,
                                                  float* __restrict__ out) {
    __shared__ float c[256];
    int g = blockIdx.x, j = threadIdx.x;
    c[j] = in[g * 256 + j];
    c[j + 128] = in[g * 256 + j + 128];
    __syncthreads();
    float acc = b[j];
    for (int k = 0; k < 256; k++) acc += c[k] * w[k * 128 + j];
    out[g * 128 + j] = fmaxf(acc, 0.f);
}

__global__ __launch_bounds__(64) void heads_kernel(const float* __restrict__ shared_in,
                                                   const float* __restrict__ w_h1, const float* __restrict__ b_h1,
                                                   const float* __restrict__ w_h2, const float* __restrict__ b_h2,
                                                   float* __restrict__ out) {
    __shared__ float sh[128];
    int bx = blockIdx.x;
    int t = bx >> 8, g = bx & 255;
    int k = threadIdx.x;
    sh[k] = shared_in[g * 128 + k];
    sh[k + 64] = shared_in[g * 128 + k + 64];
    __syncthreads();
    const float* w1 = w_h1 + (size_t)t * 128 * 64;
    float acc = b_h1[t * 64 + k];
#pragma unroll 16
    for (int d = 0; d < 128; d++) acc += sh[d] * w1[d * 64 + k];
    float p = fmaxf(acc, 0.f) * w_h2[t * 64 + k];
#pragma unroll
    for (int off = 32; off; off >>= 1) p += __shfl_xor(p, off);
    if (k == 0) out[t * 256 + g] = p + b_h2[t];
}

// ---------------------------------------------------------------------------
extern "C" void kernel_launch(void* const* d_in, const int* in_sizes, int n_in,
                              void* d_out, int out_size, void* d_ws, size_t ws_size,
                              hipStream_t stream) {
    const float* x        = (const float*)d_in[0];
    const int*   edge_idx = (const int*)  d_in[1];
    const int*   batch    = (const int*)  d_in[2];
    const float* tda      = (const float*)d_in[3];
    const float* w_in     = (const float*)d_in[4];
    const float* b_in     = (const float*)d_in[5];
    const float* w_gat    = (const float*)d_in[6];
    const float* a_src    = (const float*)d_in[7];
    const float* a_dst    = (const float*)d_in[8];
    const float* b_gat    = (const float*)d_in[9];
    const float* ln_w     = (const float*)d_in[10];
    const float* ln_b     = (const float*)d_in[11];
    const float* w_tda1   = (const float*)d_in[12];
    const float* b_tda1   = (const float*)d_in[13];
    const float* w_tda2   = (const float*)d_in[14];
    const float* b_tda2   = (const float*)d_in[15];
    const float* w_sh1    = (const float*)d_in[16];
    const float* b_sh1    = (const float*)d_in[17];
    const float* w_sh2    = (const float*)d_in[18];
    const float* b_sh2    = (const float*)d_in[19];
    const float* w_h1     = (const float*)d_in[20];
    const float* b_h1     = (const float*)d_in[21];
    const float* w_h2     = (const float*)d_in[22];
    const float* b_h2     = (const float*)d_in[23];
    float* out = (float*)d_out;

    // workspace carve-up (256B aligned)
    size_t off = 0;
    auto alloc = [&](size_t bytes) -> void* {
        void* p = (char*)d_ws + off;
        off += (bytes + 255) & ~(size_t)255;
        return p;
    };
    float*          h_a    = (float*)alloc((size_t)N_NODES * DIM * 4);
    float*          h_b    = (float*)alloc((size_t)N_NODES * DIM * 4);
    unsigned short* hb_a   = (unsigned short*)alloc((size_t)N_NODES * DIM * 2);
    unsigned short* hb_b   = (unsigned short*)alloc((size_t)N_NODES * DIM * 2);
    unsigned short* hh     = (unsigned short*)alloc((size_t)N_NODES * NHEAD * DIM * 2);
    unsigned short* wt     = (unsigned short*)alloc((size_t)NLAYER * 512 * 128 * 2);
    float*          al_sd  = (float*)alloc((size_t)2 * N_NODES * NHEAD * 4);
    float*          al_s   = al_sd;
    float*          al_d   = al_sd + (size_t)N_NODES * NHEAD;
    int*            counts = (int*)  alloc((size_t)N_NODES * 4);
    int*            cursor = (int*)  alloc((size_t)N_NODES * 4);
    int*            rowptr = (int*)  alloc((size_t)(N_NODES + 1) * 4);
    int*            csrsrc = (int*)  alloc((size_t)E_TOTAL * 4);
    float*          gmean  = (float*)alloc((size_t)N_GRAPHS * DIM * 4);
    float*          gmax   = (float*)alloc((size_t)N_GRAPHS * DIM * 4);
    float*          tda_o  = (float*)alloc((size_t)N_GRAPHS * 64 * 4);
    float*          sh1_o  = (float*)alloc((size_t)N_GRAPHS * 256 * 4);
    float*          sh2_o  = (float*)alloc((size_t)N_GRAPHS * 128 * 4);

    // CSR build
    hipMemsetAsync(counts, 0, (size_t)N_NODES * 4, stream);
    int eb = (E_TOTAL + 255) / 256;
    count_kernel<<<eb, 256, 0, stream>>>(edge_idx, counts);
    scan_kernel<<<1, 1024, 0, stream>>>(counts, rowptr, cursor, N_NODES);
    scatter_kernel<<<eb, 256, 0, stream>>>(edge_idx, cursor, csrsrc);

    // weight transpose (all layers), input projection
    wtrans_kernel<<<(NLAYER * 512 * 128 + 255) / 256, 256, 0, stream>>>(w_gat, wt);
    proj_in_kernel<<<N_NODES, 128, 0, stream>>>(x, w_in, b_in, h_a, hb_a);

    float* h_cur = h_a;  unsigned short* hb_cur = hb_a;
    float* h_nxt = h_b;  unsigned short* hb_nxt = hb_b;
    for (int l = 0; l < NLAYER; l++) {
        hipMemsetAsync(al_sd, 0, (size_t)2 * N_NODES * NHEAD * 4, stream);
        gemm_mfma_kernel<<<dim3(8, (N_NODES + 63) / 64), 256, 0, stream>>>(
            hb_cur, wt + (size_t)l * 512 * 128,
            a_src + (size_t)l * NHEAD * DIM, a_dst + (size_t)l * NHEAD * DIM,
            hh, al_s, al_d, N_NODES);
        gat_aggregate_kernel<<<N_NODES, 256, 0, stream>>>(
            hh, al_s, al_d, rowptr, csrsrc, h_cur,
            b_gat + (size_t)l * DIM, ln_w + (size_t)l * DIM, ln_b + (size_t)l * DIM,
            h_nxt, hb_nxt);
        float* t = h_cur; h_cur = h_nxt; h_nxt = t;
        unsigned short* tb = hb_cur; hb_cur = hb_nxt; hb_nxt = tb;
    }

    // pooling + MLPs
    pool_kernel<<<N_GRAPHS, 512, 0, stream>>>(h_cur, batch, gmean, gmax);
    tda_kernel<<<N_GRAPHS, 64, 0, stream>>>(tda, w_tda1, b_tda1, w_tda2, b_tda2, tda_o);
    sh1_kernel<<<N_GRAPHS, 256, 0, stream>>>(gmean, gmax, tda_o, w_sh1, b_sh1, sh1_o);
    sh2_kernel<<<N_GRAPHS, 128, 0, stream>>>(sh1_o, w_sh2, b_sh2, sh2_o);
    heads_kernel<<<NTASK * N_GRAPHS, 64, 0, stream>>>(sh2_o, w_h1, b_h1, w_h2, b_h2, out);
}

// Round 4
// 464.740 us; speedup vs baseline: 1.5609x; 1.0861x over previous
//
#include <hip/hip_runtime.h>
#include <hip/hip_bf16.h>
#include <cstdint>
#include <cstddef>

// Problem constants (match reference)
#define N_NODES  20000
#define N_EDGES  320000
#define E_TOTAL  (N_EDGES + N_NODES)   // with self loops = 340000
#define N_GRAPHS 256
#define F_NODE   11
#define F_TDA    30
#define DIM      128
#define NHEAD    4
#define NLAYER   3
#define NTASK    6
#define NEG_SLOPE 0.2f
#define LN_EPS   1e-5f

typedef short bf16x8 __attribute__((ext_vector_type(8)));
typedef float f32x4  __attribute__((ext_vector_type(4)));

// f32 -> bf16 (round-to-nearest-even), returned as raw bits
__device__ inline unsigned short f2b(float f) {
    unsigned int u = __builtin_bit_cast(unsigned int, f);
    u += 0x7fffu + ((u >> 16) & 1u);
    return (unsigned short)(u >> 16);
}
__device__ inline float blo(unsigned int u) { return __builtin_bit_cast(float, u << 16); }
__device__ inline float bhi(unsigned int u) { return __builtin_bit_cast(float, u & 0xffff0000u); }

// ---------------------------------------------------------------------------
// CSR construction (dst-grouped) — rebuilt every call (no static state)
// ---------------------------------------------------------------------------
__global__ void count_kernel(const int* __restrict__ edge_index, int* __restrict__ counts) {
    int e = blockIdx.x * 256 + threadIdx.x;
    if (e >= E_TOTAL) return;
    int d = (e < N_EDGES) ? edge_index[N_EDGES + e] : (e - N_EDGES);
    atomicAdd(&counts[d], 1);
}

__global__ __launch_bounds__(1024) void scan_kernel(const int* __restrict__ counts,
                                                    int* __restrict__ row_ptr,
                                                    int* __restrict__ cursor, int n) {
    __shared__ int wsum[16];
    __shared__ int carry_s;
    int tid = threadIdx.x;
    int wave = tid >> 6, lane = tid & 63;
    if (tid == 0) carry_s = 0;
    __syncthreads();
    for (int base = 0; base < n; base += 1024) {
        int i = base + tid;
        int v = (i < n) ? counts[i] : 0;
        int x = v;
#pragma unroll
        for (int off = 1; off < 64; off <<= 1) {
            int y = __shfl_up(x, off);
            if (lane >= off) x += y;
        }
        if (lane == 63) wsum[wave] = x;
        __syncthreads();
        if (wave == 0 && lane < 16) {
            int w = wsum[lane];
#pragma unroll
            for (int off = 1; off < 16; off <<= 1) {
                int y = __shfl_up(w, off);
                if (lane >= off) w += y;
            }
            wsum[lane] = w;
        }
        __syncthreads();
        int woff = (wave == 0) ? 0 : wsum[wave - 1];
        int incl = carry_s + woff + x;
        if (i < n) { int r = incl - v; row_ptr[i] = r; cursor[i] = r; }
        __syncthreads();
        if (tid == 1023) carry_s = incl;
        __syncthreads();
    }
    if (tid == 0) row_ptr[n] = carry_s;
}

__global__ void scatter_kernel(const int* __restrict__ edge_index, int* __restrict__ cursor,
                               int* __restrict__ csr_src) {
    int e = blockIdx.x * 256 + threadIdx.x;
    if (e >= E_TOTAL) return;
    int s, d;
    if (e < N_EDGES) { s = edge_index[e]; d = edge_index[N_EDGES + e]; }
    else             { s = e - N_EDGES;   d = s; }
    int pos = atomicAdd(&cursor[d], 1);
    csr_src[pos] = s;
}

// ---------------------------------------------------------------------------
// Input projection: h = relu(x @ w_in + b_in); writes f32 + bf16 copies
// ---------------------------------------------------------------------------
__global__ __launch_bounds__(128) void proj_in_kernel(const float* __restrict__ x,
                                                      const float* __restrict__ w,
                                                      const float* __restrict__ b,
                                                      float* __restrict__ h,
                                                      unsigned short* __restrict__ h_bf) {
    __shared__ float xr[F_NODE];
    int n = blockIdx.x, d = threadIdx.x;
    if (d < F_NODE) xr[d] = x[n * F_NODE + d];
    __syncthreads();
    float acc = b[d];
#pragma unroll
    for (int k = 0; k < F_NODE; k++) acc += xr[k] * w[k * DIM + d];
    float v = fmaxf(acc, 0.f);
    h[(size_t)n * DIM + d] = v;
    h_bf[(size_t)n * DIM + d] = f2b(v);
}

// ---------------------------------------------------------------------------
// Weight transpose+cast: w_gat [L][128][512] f32 -> Wt [L][512][128] bf16
// ---------------------------------------------------------------------------
__global__ __launch_bounds__(256) void wtrans_kernel(const float* __restrict__ w_gat,
                                                     unsigned short* __restrict__ wt) {
    int i = blockIdx.x * 256 + threadIdx.x;   // over L*512*128
    if (i >= NLAYER * 512 * 128) return;
    int k = i & 127;
    int n = (i >> 7) & 511;
    int l = i >> 16;
    wt[i] = f2b(w_gat[(size_t)l * 65536 + (size_t)k * 512 + n]);
}

// ---------------------------------------------------------------------------
// MFMA GEMM: hh = h_bf @ W   [M,128]bf16 @ [128,512]bf16 -> [M,512] bf16
// + fused alpha partials: al_s/al_d += (hh_tile) . a_src/a_dst  (atomicAdd)
// 64x64 tile, 4 waves, 16x16x32 MFMA, K=128 in 4 steps.
// ---------------------------------------------------------------------------
__global__ __launch_bounds__(256) void gemm_mfma_kernel(const unsigned short* __restrict__ A,
                                                        const unsigned short* __restrict__ Bt,
                                                        const float* __restrict__ a_sl,
                                                        const float* __restrict__ a_dl,
                                                        unsigned short* __restrict__ C,
                                                        float* __restrict__ al_s_out,
                                                        float* __restrict__ al_d_out, int M) {
    // row pitch 136 bf16 = 272 B (16B-aligned, +8 pad kills b128 bank conflicts)
    __shared__ __align__(16) unsigned short As[64 * 136];
    __shared__ __align__(16) unsigned short Bs[64 * 136];
    int tid = threadIdx.x;
    int m0 = blockIdx.y << 6, n0 = blockIdx.x << 6;

    const uint4 zero4 = make_uint4(0, 0, 0, 0);
#pragma unroll
    for (int p = 0; p < 4; p++) {
        int i = p * 256 + tid;          // 1024 = 64 rows * 16 k-groups
        int row = i >> 4, kg = i & 15;
        int arow = m0 + row;
        uint4 av = (arow < M) ? *(const uint4*)(A + (size_t)arow * 128 + kg * 8) : zero4;
        *(uint4*)&As[row * 136 + kg * 8] = av;
        uint4 bv = *(const uint4*)(Bt + (size_t)(n0 + row) * 128 + kg * 8);
        *(uint4*)&Bs[row * 136 + kg * 8] = bv;
    }
    __syncthreads();

    int wave = tid >> 6, lane = tid & 63;
    int lr = lane & 15, lg = lane >> 4;
    f32x4 acc[4] = {};
#pragma unroll
    for (int ks = 0; ks < 4; ks++) {
        bf16x8 af = *(const bf16x8*)&As[(wave * 16 + lr) * 136 + ks * 32 + lg * 8];
#pragma unroll
        for (int nt = 0; nt < 4; nt++) {
            bf16x8 bf_ = *(const bf16x8*)&Bs[(nt * 16 + lr) * 136 + ks * 32 + lg * 8];
            acc[nt] = __builtin_amdgcn_mfma_f32_16x16x32_bf16(af, bf_, acc[nt], 0, 0, 0);
        }
    }
    // store hh: row = m0 + wave*16 + lg*4 + r ; col = n0 + nt*16 + lr
#pragma unroll
    for (int nt = 0; nt < 4; nt++) {
#pragma unroll
        for (int r = 0; r < 4; r++) {
            int row = m0 + wave * 16 + lg * 4 + r;
            if (row < M) C[(size_t)row * 512 + n0 + nt * 16 + lr] = f2b(acc[nt][r]);
        }
    }

    // fused alpha partial dots for this block's 64 cols (all within head hblk)
    int hblk = n0 >> 7;
    int cbase = n0 & 127;
    float asv[4], adv[4];
#pragma unroll
    for (int nt = 0; nt < 4; nt++) {
        asv[nt] = a_sl[hblk * 128 + cbase + nt * 16 + lr];
        adv[nt] = a_dl[hblk * 128 + cbase + nt * 16 + lr];
    }
#pragma unroll
    for (int r = 0; r < 4; r++) {
        float ps = 0.f, pd = 0.f;
#pragma unroll
        for (int nt = 0; nt < 4; nt++) { ps += acc[nt][r] * asv[nt]; pd += acc[nt][r] * adv[nt]; }
#pragma unroll
        for (int off = 8; off; off >>= 1) { ps += __shfl_xor(ps, off); pd += __shfl_xor(pd, off); }
        int row = m0 + wave * 16 + lg * 4 + r;
        if (lr == 0 && row < M) {
            atomicAdd(&al_s_out[row * 4 + hblk], ps);
            atomicAdd(&al_d_out[row * 4 + hblk], pd);
        }
    }
}

// ---------------------------------------------------------------------------
// Wave-per-node GAT tail, SINGLE PASS, no barriers, no LDS:
//   softmax without max subtraction (exp can't overflow; clamp at 60):
//   out = (sum_e exp(v_e) * hh[src_e]) / (sum_e exp(v_e))
// lane owns 8 contiguous features of [H*D=512]; its head = lane>>4, so the
// per-head denominator is identical across the 16 lanes of a head (no reduce).
// Head-mean via shfl_xor(16,32); LayerNorm via shfl_xor(1,2,4,8).
// 4 nodes per 256-thread block (one per wave).
// ---------------------------------------------------------------------------
__global__ __launch_bounds__(256) void gat_aggregate_kernel(
    const unsigned short* __restrict__ hh, const float* __restrict__ al_s,
    const float* __restrict__ al_d, const int* __restrict__ row_ptr,
    const int* __restrict__ csr_src, const float* __restrict__ h_in,
    const float* __restrict__ b_gat, const float* __restrict__ ln_w,
    const float* __restrict__ ln_b, float* __restrict__ h_out,
    unsigned short* __restrict__ h_out_bf) {
    int wave = threadIdx.x >> 6, lane = threadIdx.x & 63;
    int n = blockIdx.x * 4 + wave;
    if (n >= N_NODES) return;

    int begin = row_ptr[n];
    int deg = row_ptr[n + 1] - begin;    // >= 1 (self loop)
    int hl = lane >> 4;                  // head of this lane's 8 features
    float adh = al_d[n * 4 + hl];

    float acc[8] = {};
    float ls = 0.f;
    const int* __restrict__ srcp = csr_src + begin;
    for (int e = 0; e < deg; e++) {
        int s = srcp[e];
        float v = al_s[s * 4 + hl] + adh;
        v = (v > 0.f) ? v : NEG_SLOPE * v;
        v = fminf(v, 60.f);
        float w = __expf(v);
        ls += w;
        uint4 u = *(const uint4*)(hh + (size_t)s * 512 + lane * 8);
        acc[0] += w * blo(u.x); acc[1] += w * bhi(u.x);
        acc[2] += w * blo(u.y); acc[3] += w * bhi(u.y);
        acc[4] += w * blo(u.z); acc[5] += w * bhi(u.z);
        acc[6] += w * blo(u.w); acc[7] += w * bhi(u.w);
    }
    float il = 1.f / ls;
#pragma unroll
    for (int j = 0; j < 8; j++) acc[j] *= il;

    // head mean: lanes l, l^16, l^32, l^48 hold the 4 heads of base features
    // (l&15)*8..+7 — sum them, then *0.25
#pragma unroll
    for (int j = 0; j < 8; j++) {
        acc[j] += __shfl_xor(acc[j], 16);
        acc[j] += __shfl_xor(acc[j], 32);
    }
    int fb = (lane & 15) * 8;
    float4 bg0 = *(const float4*)(b_gat + fb);
    float4 bg1 = *(const float4*)(b_gat + fb + 4);
    float g[8];
    g[0] = acc[0] * 0.25f + bg0.x; g[1] = acc[1] * 0.25f + bg0.y;
    g[2] = acc[2] * 0.25f + bg0.z; g[3] = acc[3] * 0.25f + bg0.w;
    g[4] = acc[4] * 0.25f + bg1.x; g[5] = acc[5] * 0.25f + bg1.y;
    g[6] = acc[6] * 0.25f + bg1.z; g[7] = acc[7] * 0.25f + bg1.w;

    // LayerNorm over 128 feats: reduce within each 16-lane group (values
    // replicated across groups, so any group computes the same stats)
    float s1 = 0.f;
#pragma unroll
    for (int j = 0; j < 8; j++) s1 += g[j];
#pragma unroll
    for (int off = 1; off < 16; off <<= 1) s1 += __shfl_xor(s1, off);
    float mu = s1 * (1.f / 128.f);
    float s2 = 0.f;
#pragma unroll
    for (int j = 0; j < 8; j++) { float d = g[j] - mu; s2 += d * d; }
#pragma unroll
    for (int off = 1; off < 16; off <<= 1) s2 += __shfl_xor(s2, off);
    float rstd = rsqrtf(s2 * (1.f / 128.f) + LN_EPS);

    if (lane < 16) {
        float4 lw0 = *(const float4*)(ln_w + fb);
        float4 lw1 = *(const float4*)(ln_w + fb + 4);
        float4 lb0 = *(const float4*)(ln_b + fb);
        float4 lb1 = *(const float4*)(ln_b + fb + 4);
        float4 hi0 = *(const float4*)(h_in + (size_t)n * DIM + fb);
        float4 hi1 = *(const float4*)(h_in + (size_t)n * DIM + fb + 4);
        float o[8];
        o[0] = fmaxf((g[0] - mu) * rstd * lw0.x + lb0.x, 0.f) + hi0.x;
        o[1] = fmaxf((g[1] - mu) * rstd * lw0.y + lb0.y, 0.f) + hi0.y;
        o[2] = fmaxf((g[2] - mu) * rstd * lw0.z + lb0.z, 0.f) + hi0.z;
        o[3] = fmaxf((g[3] - mu) * rstd * lw0.w + lb0.w, 0.f) + hi0.w;
        o[4] = fmaxf((g[4] - mu) * rstd * lw1.x + lb1.x, 0.f) + hi1.x;
        o[5] = fmaxf((g[5] - mu) * rstd * lw1.y + lb1.y, 0.f) + hi1.y;
        o[6] = fmaxf((g[6] - mu) * rstd * lw1.z + lb1.z, 0.f) + hi1.z;
        o[7] = fmaxf((g[7] - mu) * rstd * lw1.w + lb1.w, 0.f) + hi1.w;
        *(float4*)(h_out + (size_t)n * DIM + fb)     = make_float4(o[0], o[1], o[2], o[3]);
        *(float4*)(h_out + (size_t)n * DIM + fb + 4) = make_float4(o[4], o[5], o[6], o[7]);
        uint4 pb;
        pb.x = (unsigned)f2b(o[0]) | ((unsigned)f2b(o[1]) << 16);
        pb.y = (unsigned)f2b(o[2]) | ((unsigned)f2b(o[3]) << 16);
        pb.z = (unsigned)f2b(o[4]) | ((unsigned)f2b(o[5]) << 16);
        pb.w = (unsigned)f2b(o[6]) | ((unsigned)f2b(o[7]) << 16);
        *(uint4*)(h_out_bf + (size_t)n * DIM + fb) = pb;
    }
}

// ---------------------------------------------------------------------------
// Graph pooling: mean + max per graph (batch sorted -> binary search range)
// 512 threads: 4 node-slices x 128 features, LDS combine.
// ---------------------------------------------------------------------------
__device__ int lower_bound_dev(const int* a, int n, int v) {
    int lo = 0, hi = n;
    while (lo < hi) { int mid = (lo + hi) >> 1; if (a[mid] < v) lo = mid + 1; else hi = mid; }
    return lo;
}

__global__ __launch_bounds__(512) void pool_kernel(const float* __restrict__ h,
                                                   const int* __restrict__ batch,
                                                   float* __restrict__ gmean,
                                                   float* __restrict__ gmax) {
    __shared__ float ssum[4][128];
    __shared__ float smax[4][128];
    __shared__ int bounds[2];
    int g = blockIdx.x;
    int tid = threadIdx.x;
    if (tid < 2) bounds[tid] = lower_bound_dev(batch, N_NODES, g + tid);
    __syncthreads();
    int lo = bounds[0], hi = bounds[1];
    int q = tid >> 7, d = tid & 127;
    float s = 0.f, m = -1e30f;
    for (int i = lo + q; i < hi; i += 4) {
        float v = h[(size_t)i * DIM + d];
        s += v; m = fmaxf(m, v);
    }
    ssum[q][d] = s; smax[q][d] = m;
    __syncthreads();
    if (tid < 128) {
        float S = ssum[0][d] + ssum[1][d] + ssum[2][d] + ssum[3][d];
        float M = fmaxf(fmaxf(smax[0][d], smax[1][d]), fmaxf(smax[2][d], smax[3][d]));
        int cnt = hi - lo;
        gmean[g * DIM + d] = S / fmaxf((float)cnt, 1.f);
        gmax[g * DIM + d]  = (cnt > 0) ? M : 0.f;
    }
}

// ---------------------------------------------------------------------------
// TDA MLP + trunk + heads (tiny)
// ---------------------------------------------------------------------------
__global__ __launch_bounds__(64) void tda_kernel(const float* __restrict__ tda,
                                                 const float* __restrict__ w1, const float* __restrict__ b1,
                                                 const float* __restrict__ w2, const float* __restrict__ b2,
                                                 float* __restrict__ out) {
    __shared__ float tr[F_TDA];
    __shared__ float t1[64];
    int g = blockIdx.x, j = threadIdx.x;
    if (j < F_TDA) tr[j] = tda[g * F_TDA + j];
    __syncthreads();
    float acc = b1[j];
#pragma unroll
    for (int k = 0; k < F_TDA; k++) acc += tr[k] * w1[k * 64 + j];
    t1[j] = fmaxf(acc, 0.f);
    __syncthreads();
    float acc2 = b2[j];
#pragma unroll
    for (int k = 0; k < 64; k++) acc2 += t1[k] * w2[k * 64 + j];
    out[g * 64 + j] = fmaxf(acc2, 0.f);
}

__global__ __launch_bounds__(256) void sh1_kernel(const float* __restrict__ gmean,
                                                  const float* __restrict__ gmax,
                                                  const float* __restrict__ tda_o,
                                                  const float* __restrict__ w, const float* __restrict__ b,
                                                  float* __restrict__ out) {
    __shared__ float c[320];
    int g = blockIdx.x, j = threadIdx.x;
    if (j < 128) c[j] = gmean[g * 128 + j];
    else         c[j] = gmax[g * 128 + (j - 128)];
    if (j < 64)  c[256 + j] = tda_o[g * 64 + j];
    __syncthreads();
    float acc = b[j];
    for (int k = 0; k < 320; k++) acc += c[k] * w[k * 256 + j];
    out[g * 256 + j] = fmaxf(acc, 0.f);
}

__global__ __launch_bounds__(128) void sh2_kernel(const float* __restrict__ in,
                                                  const float* __restrict__ w, const float* __restrict__ b,
                                                  float* __restrict__ out) {
    __shared__ float c[256];
    int g = blockIdx.x, j = threadIdx.x;
    c[j] = in[g * 256 + j];
    c[j + 128] = in[g * 256 + j + 128];
    __syncthreads();
    float acc = b[j];
    for (int k = 0; k < 256; k++) acc += c[k] * w[k * 128 + j];
    out[g * 128 + j] = fmaxf(acc, 0.f);
}

__global__ __launch_bounds__(64) void heads_kernel(const float* __restrict__ shared_in,
                                                   const float* __restrict__ w_h1, const float* __restrict__ b_h1,
                                                   const float* __restrict__ w_h2, const float* __restrict__ b_h2,
                                                   float* __restrict__ out) {
    __shared__ float sh[128];
    int bx = blockIdx.x;
    int t = bx >> 8, g = bx & 255;
    int k = threadIdx.x;
    sh[k] = shared_in[g * 128 + k];
    sh[k + 64] = shared_in[g * 128 + k + 64];
    __syncthreads();
    const float* w1 = w_h1 + (size_t)t * 128 * 64;
    float acc = b_h1[t * 64 + k];
#pragma unroll 16
    for (int d = 0; d < 128; d++) acc += sh[d] * w1[d * 64 + k];
    float p = fmaxf(acc, 0.f) * w_h2[t * 64 + k];
#pragma unroll
    for (int off = 32; off; off >>= 1) p += __shfl_xor(p, off);
    if (k == 0) out[t * 256 + g] = p + b_h2[t];
}

// ---------------------------------------------------------------------------
extern "C" void kernel_launch(void* const* d_in, const int* in_sizes, int n_in,
                              void* d_out, int out_size, void* d_ws, size_t ws_size,
                              hipStream_t stream) {
    const float* x        = (const float*)d_in[0];
    const int*   edge_idx = (const int*)  d_in[1];
    const int*   batch    = (const int*)  d_in[2];
    const float* tda      = (const float*)d_in[3];
    const float* w_in     = (const float*)d_in[4];
    const float* b_in     = (const float*)d_in[5];
    const float* w_gat    = (const float*)d_in[6];
    const float* a_src    = (const float*)d_in[7];
    const float* a_dst    = (const float*)d_in[8];
    const float* b_gat    = (const float*)d_in[9];
    const float* ln_w     = (const float*)d_in[10];
    const float* ln_b     = (const float*)d_in[11];
    const float* w_tda1   = (const float*)d_in[12];
    const float* b_tda1   = (const float*)d_in[13];
    const float* w_tda2   = (const float*)d_in[14];
    const float* b_tda2   = (const float*)d_in[15];
    const float* w_sh1    = (const float*)d_in[16];
    const float* b_sh1    = (const float*)d_in[17];
    const float* w_sh2    = (const float*)d_in[18];
    const float* b_sh2    = (const float*)d_in[19];
    const float* w_h1     = (const float*)d_in[20];
    const float* b_h1     = (const float*)d_in[21];
    const float* w_h2     = (const float*)d_in[22];
    const float* b_h2     = (const float*)d_in[23];
    float* out = (float*)d_out;

    // workspace carve-up (256B aligned)
    size_t off = 0;
    auto alloc = [&](size_t bytes) -> void* {
        void* p = (char*)d_ws + off;
        off += (bytes + 255) & ~(size_t)255;
        return p;
    };
    float*          h_a    = (float*)alloc((size_t)N_NODES * DIM * 4);
    float*          h_b    = (float*)alloc((size_t)N_NODES * DIM * 4);
    unsigned short* hb_a   = (unsigned short*)alloc((size_t)N_NODES * DIM * 2);
    unsigned short* hb_b   = (unsigned short*)alloc((size_t)N_NODES * DIM * 2);
    unsigned short* hh     = (unsigned short*)alloc((size_t)N_NODES * NHEAD * DIM * 2);
    unsigned short* wt     = (unsigned short*)alloc((size_t)NLAYER * 512 * 128 * 2);
    float*          al_sd  = (float*)alloc((size_t)2 * N_NODES * NHEAD * 4);
    float*          al_s   = al_sd;
    float*          al_d   = al_sd + (size_t)N_NODES * NHEAD;
    int*            counts = (int*)  alloc((size_t)N_NODES * 4);
    int*            cursor = (int*)  alloc((size_t)N_NODES * 4);
    int*            rowptr = (int*)  alloc((size_t)(N_NODES + 1) * 4);
    int*            csrsrc = (int*)  alloc((size_t)E_TOTAL * 4);
    float*          gmean  = (float*)alloc((size_t)N_GRAPHS * DIM * 4);
    float*          gmax   = (float*)alloc((size_t)N_GRAPHS * DIM * 4);
    float*          tda_o  = (float*)alloc((size_t)N_GRAPHS * 64 * 4);
    float*          sh1_o  = (float*)alloc((size_t)N_GRAPHS * 256 * 4);
    float*          sh2_o  = (float*)alloc((size_t)N_GRAPHS * 128 * 4);

    // CSR build
    hipMemsetAsync(counts, 0, (size_t)N_NODES * 4, stream);
    int eb = (E_TOTAL + 255) / 256;
    count_kernel<<<eb, 256, 0, stream>>>(edge_idx, counts);
    scan_kernel<<<1, 1024, 0, stream>>>(counts, rowptr, cursor, N_NODES);
    scatter_kernel<<<eb, 256, 0, stream>>>(edge_idx, cursor, csrsrc);

    // weight transpose (all layers), input projection
    wtrans_kernel<<<(NLAYER * 512 * 128 + 255) / 256, 256, 0, stream>>>(w_gat, wt);
    proj_in_kernel<<<N_NODES, 128, 0, stream>>>(x, w_in, b_in, h_a, hb_a);

    float* h_cur = h_a;  unsigned short* hb_cur = hb_a;
    float* h_nxt = h_b;  unsigned short* hb_nxt = hb_b;
    for (int l = 0; l < NLAYER; l++) {
        hipMemsetAsync(al_sd, 0, (size_t)2 * N_NODES * NHEAD * 4, stream);
        gemm_mfma_kernel<<<dim3(8, (N_NODES + 63) / 64), 256, 0, stream>>>(
            hb_cur, wt + (size_t)l * 512 * 128,
            a_src + (size_t)l * NHEAD * DIM, a_dst + (size_t)l * NHEAD * DIM,
            hh, al_s, al_d, N_NODES);
        gat_aggregate_kernel<<<(N_NODES + 3) / 4, 256, 0, stream>>>(
            hh, al_s, al_d, rowptr, csrsrc, h_cur,
            b_gat + (size_t)l * DIM, ln_w + (size_t)l * DIM, ln_b + (size_t)l * DIM,
            h_nxt, hb_nxt);
        float* t = h_cur; h_cur = h_nxt; h_nxt = t;
        unsigned short* tb = hb_cur; hb_cur = hb_nxt; hb_nxt = tb;
    }

    // pooling + MLPs
    pool_kernel<<<N_GRAPHS, 512, 0, stream>>>(h_cur, batch, gmean, gmax);
    tda_kernel<<<N_GRAPHS, 64, 0, stream>>>(tda, w_tda1, b_tda1, w_tda2, b_tda2, tda_o);
    sh1_kernel<<<N_GRAPHS, 256, 0, stream>>>(gmean, gmax, tda_o, w_sh1, b_sh1, sh1_o);
    sh2_kernel<<<N_GRAPHS, 128, 0, stream>>>(sh1_o, w_sh2, b_sh2, sh2_o);
    heads_kernel<<<NTASK * N_GRAPHS, 64, 0, stream>>>(sh2_o, w_h1, b_h1, w_h2, b_h2, out);
}

// Round 5
// 384.773 us; speedup vs baseline: 1.8852x; 1.2078x over previous
//
#include <hip/hip_runtime.h>
#include <hip/hip_bf16.h>
#include <cstdint>
#include <cstddef>

// Problem constants (match reference)
#define N_NODES  20000
#define N_EDGES  320000
#define E_TOTAL  (N_EDGES + N_NODES)   // with self loops = 340000
#define N_GRAPHS 256
#define F_NODE   11
#define F_TDA    30
#define DIM      128
#define NHEAD    4
#define NLAYER   3
#define NTASK    6
#define NEG_SLOPE 0.2f
#define LN_EPS   1e-5f

typedef short bf16x8 __attribute__((ext_vector_type(8)));
typedef float f32x4  __attribute__((ext_vector_type(4)));

// f32 -> bf16 (round-to-nearest-even), returned as raw bits
__device__ inline unsigned short f2b(float f) {
    unsigned int u = __builtin_bit_cast(unsigned int, f);
    u += 0x7fffu + ((u >> 16) & 1u);
    return (unsigned short)(u >> 16);
}
__device__ inline float blo(unsigned int u) { return __builtin_bit_cast(float, u << 16); }
__device__ inline float bhi(unsigned int u) { return __builtin_bit_cast(float, u & 0xffff0000u); }

// ---------------------------------------------------------------------------
// CSR construction (dst-grouped) — rebuilt every call (no static state)
// ---------------------------------------------------------------------------
__global__ void count_kernel(const int* __restrict__ edge_index, int* __restrict__ counts) {
    int e = blockIdx.x * 256 + threadIdx.x;
    if (e >= E_TOTAL) return;
    int d = (e < N_EDGES) ? edge_index[N_EDGES + e] : (e - N_EDGES);
    atomicAdd(&counts[d], 1);
}

// Parallel scan: 20 blocks; block b redundantly sums counts[0..b*1024) for its
// base, then shuffle-scans its own 1024 chunk. Fully parallel, 2 barriers.
__global__ __launch_bounds__(1024) void scan_kernel(const int* __restrict__ counts,
                                                    int* __restrict__ row_ptr,
                                                    int* __restrict__ cursor) {
    __shared__ int redw[16];
    __shared__ int wsum[16];
    int b = blockIdx.x;
    int tid = threadIdx.x;
    int lane = tid & 63, wave = tid >> 6;
    int base = b * 1024;

    // prefix-base: sum of counts[0..base)
    int bs = 0;
    for (int i = tid; i < base; i += 1024) bs += counts[i];
#pragma unroll
    for (int off = 32; off; off >>= 1) bs += __shfl_xor(bs, off);
    if (lane == 0) redw[wave] = bs;

    // own chunk inclusive scan
    int i = base + tid;
    int v = (i < N_NODES) ? counts[i] : 0;
    int x = v;
#pragma unroll
    for (int off = 1; off < 64; off <<= 1) {
        int y = __shfl_up(x, off);
        if (lane >= off) x += y;
    }
    if (lane == 63) wsum[wave] = x;
    __syncthreads();

    int blockbase = 0;
#pragma unroll
    for (int w = 0; w < 16; w++) blockbase += redw[w];

    if (tid < 16) {
        int w = wsum[tid];
#pragma unroll
        for (int off = 1; off < 16; off <<= 1) {
            int y = __shfl_up(w, off);
            if (tid >= off) w += y;
        }
        wsum[tid] = w;
    }
    __syncthreads();
    int woff = wave ? wsum[wave - 1] : 0;
    int incl = blockbase + woff + x;
    int excl = incl - v;
    if (i < N_NODES) { row_ptr[i] = excl; cursor[i] = excl; }
    if (i == N_NODES - 1) row_ptr[N_NODES] = incl;
}

__global__ void scatter_kernel(const int* __restrict__ edge_index, int* __restrict__ cursor,
                               int* __restrict__ csr_src) {
    int e = blockIdx.x * 256 + threadIdx.x;
    if (e >= E_TOTAL) return;
    int s, d;
    if (e < N_EDGES) { s = edge_index[e]; d = edge_index[N_EDGES + e]; }
    else             { s = e - N_EDGES;   d = s; }
    int pos = atomicAdd(&cursor[d], 1);
    csr_src[pos] = s;
}

// ---------------------------------------------------------------------------
// Input projection: h = relu(x @ w_in + b_in); writes f32 + bf16 copies
// ---------------------------------------------------------------------------
__global__ __launch_bounds__(128) void proj_in_kernel(const float* __restrict__ x,
                                                      const float* __restrict__ w,
                                                      const float* __restrict__ b,
                                                      float* __restrict__ h,
                                                      unsigned short* __restrict__ h_bf) {
    __shared__ float xr[F_NODE];
    int n = blockIdx.x, d = threadIdx.x;
    if (d < F_NODE) xr[d] = x[n * F_NODE + d];
    __syncthreads();
    float acc = b[d];
#pragma unroll
    for (int k = 0; k < F_NODE; k++) acc += xr[k] * w[k * DIM + d];
    float v = fmaxf(acc, 0.f);
    h[(size_t)n * DIM + d] = v;
    h_bf[(size_t)n * DIM + d] = f2b(v);
}

// ---------------------------------------------------------------------------
// Weight transpose+cast: w_gat [L][128][512] f32 -> Wt [L][512][128] bf16
// ---------------------------------------------------------------------------
__global__ __launch_bounds__(256) void wtrans_kernel(const float* __restrict__ w_gat,
                                                     unsigned short* __restrict__ wt) {
    int i = blockIdx.x * 256 + threadIdx.x;   // over L*512*128
    if (i >= NLAYER * 512 * 128) return;
    int k = i & 127;
    int n = (i >> 7) & 511;
    int l = i >> 16;
    wt[i] = f2b(w_gat[(size_t)l * 65536 + (size_t)k * 512 + n]);
}

// ---------------------------------------------------------------------------
// MFMA GEMM, head-aligned: grid (4, M/64). Block computes 64 rows x 128 cols
// (one full head) -> alpha dot completes in-block, direct store (no atomics).
// ---------------------------------------------------------------------------
__global__ __launch_bounds__(256) void gemm_mfma_kernel(const unsigned short* __restrict__ A,
                                                        const unsigned short* __restrict__ Bt,
                                                        const float* __restrict__ a_sl,
                                                        const float* __restrict__ a_dl,
                                                        unsigned short* __restrict__ C,
                                                        float* __restrict__ al_s_out,
                                                        float* __restrict__ al_d_out, int M) {
    // row pitch 136 bf16 = 272 B (16B-aligned, pad kills b128 bank conflicts)
    __shared__ __align__(16) unsigned short As[64 * 136];
    __shared__ __align__(16) unsigned short Bs[128 * 136];
    int tid = threadIdx.x;
    int hblk = blockIdx.x;              // head index, n0 = hblk*128
    int m0 = blockIdx.y << 6;
    int n0 = hblk << 7;

    const uint4 zero4 = make_uint4(0, 0, 0, 0);
#pragma unroll
    for (int p = 0; p < 4; p++) {       // A: 64 rows x 16 k-groups
        int i = p * 256 + tid;
        int row = i >> 4, kg = i & 15;
        int arow = m0 + row;
        uint4 av = (arow < M) ? *(const uint4*)(A + (size_t)arow * 128 + kg * 8) : zero4;
        *(uint4*)&As[row * 136 + kg * 8] = av;
    }
#pragma unroll
    for (int p = 0; p < 8; p++) {       // B: 128 n-rows x 16 k-groups
        int i = p * 256 + tid;
        int row = i >> 4, kg = i & 15;
        uint4 bv = *(const uint4*)(Bt + (size_t)(n0 + row) * 128 + kg * 8);
        *(uint4*)&Bs[row * 136 + kg * 8] = bv;
    }
    __syncthreads();

    int wave = tid >> 6, lane = tid & 63;
    int lr = lane & 15, lg = lane >> 4;
    f32x4 acc[8] = {};
#pragma unroll
    for (int ks = 0; ks < 4; ks++) {
        bf16x8 af = *(const bf16x8*)&As[(wave * 16 + lr) * 136 + ks * 32 + lg * 8];
#pragma unroll
        for (int nt = 0; nt < 8; nt++) {
            bf16x8 bf_ = *(const bf16x8*)&Bs[(nt * 16 + lr) * 136 + ks * 32 + lg * 8];
            acc[nt] = __builtin_amdgcn_mfma_f32_16x16x32_bf16(af, bf_, acc[nt], 0, 0, 0);
        }
    }
    // store hh: row = m0 + wave*16 + lg*4 + r ; col = n0 + nt*16 + lr
#pragma unroll
    for (int nt = 0; nt < 8; nt++) {
#pragma unroll
        for (int r = 0; r < 4; r++) {
            int row = m0 + wave * 16 + lg * 4 + r;
            if (row < M) C[(size_t)row * 512 + n0 + nt * 16 + lr] = f2b(acc[nt][r]);
        }
    }

    // alpha dots for head hblk (complete within this block)
    float asv[8], adv[8];
#pragma unroll
    for (int nt = 0; nt < 8; nt++) {
        asv[nt] = a_sl[hblk * 128 + nt * 16 + lr];
        adv[nt] = a_dl[hblk * 128 + nt * 16 + lr];
    }
#pragma unroll
    for (int r = 0; r < 4; r++) {
        float ps = 0.f, pd = 0.f;
#pragma unroll
        for (int nt = 0; nt < 8; nt++) { ps += acc[nt][r] * asv[nt]; pd += acc[nt][r] * adv[nt]; }
#pragma unroll
        for (int off = 8; off; off >>= 1) { ps += __shfl_xor(ps, off); pd += __shfl_xor(pd, off); }
        int row = m0 + wave * 16 + lg * 4 + r;
        if (lr == 0 && row < M) {
            al_s_out[row * 4 + hblk] = ps;
            al_d_out[row * 4 + hblk] = pd;
        }
    }
}

// ---------------------------------------------------------------------------
// Wave-per-node GAT tail, single pass, no barriers/LDS; edge loop unrolled x4
// so 4 gathers are in flight per wave.
// ---------------------------------------------------------------------------
__global__ __launch_bounds__(256) void gat_aggregate_kernel(
    const unsigned short* __restrict__ hh, const float* __restrict__ al_s,
    const float* __restrict__ al_d, const int* __restrict__ row_ptr,
    const int* __restrict__ csr_src, const float* __restrict__ h_in,
    const float* __restrict__ b_gat, const float* __restrict__ ln_w,
    const float* __restrict__ ln_b, float* __restrict__ h_out,
    unsigned short* __restrict__ h_out_bf) {
    int wave = threadIdx.x >> 6, lane = threadIdx.x & 63;
    int n = blockIdx.x * 4 + wave;
    if (n >= N_NODES) return;

    int begin = row_ptr[n];
    int deg = row_ptr[n + 1] - begin;    // >= 1 (self loop)
    int hl = lane >> 4;                  // head of this lane's 8 features
    float adh = al_d[n * 4 + hl];
    const int* __restrict__ srcp = csr_src + begin;
    size_t lo8 = (size_t)(lane * 8);

    float acc[8] = {};
    float ls = 0.f;
    int e = 0;
    for (; e + 4 <= deg; e += 4) {
        int s0 = srcp[e + 0], s1 = srcp[e + 1], s2 = srcp[e + 2], s3 = srcp[e + 3];
        float a0 = al_s[s0 * 4 + hl], a1 = al_s[s1 * 4 + hl];
        float a2 = al_s[s2 * 4 + hl], a3 = al_s[s3 * 4 + hl];
        uint4 u0 = *(const uint4*)(hh + (size_t)s0 * 512 + lo8);
        uint4 u1 = *(const uint4*)(hh + (size_t)s1 * 512 + lo8);
        uint4 u2 = *(const uint4*)(hh + (size_t)s2 * 512 + lo8);
        uint4 u3 = *(const uint4*)(hh + (size_t)s3 * 512 + lo8);
        float v0 = a0 + adh; v0 = (v0 > 0.f) ? v0 : NEG_SLOPE * v0;
        float v1 = a1 + adh; v1 = (v1 > 0.f) ? v1 : NEG_SLOPE * v1;
        float v2 = a2 + adh; v2 = (v2 > 0.f) ? v2 : NEG_SLOPE * v2;
        float v3 = a3 + adh; v3 = (v3 > 0.f) ? v3 : NEG_SLOPE * v3;
        float w0 = __expf(fminf(v0, 60.f));
        float w1 = __expf(fminf(v1, 60.f));
        float w2 = __expf(fminf(v2, 60.f));
        float w3 = __expf(fminf(v3, 60.f));
        ls += (w0 + w1) + (w2 + w3);
        acc[0] += w0 * blo(u0.x) + w1 * blo(u1.x) + w2 * blo(u2.x) + w3 * blo(u3.x);
        acc[1] += w0 * bhi(u0.x) + w1 * bhi(u1.x) + w2 * bhi(u2.x) + w3 * bhi(u3.x);
        acc[2] += w0 * blo(u0.y) + w1 * blo(u1.y) + w2 * blo(u2.y) + w3 * blo(u3.y);
        acc[3] += w0 * bhi(u0.y) + w1 * bhi(u1.y) + w2 * bhi(u2.y) + w3 * bhi(u3.y);
        acc[4] += w0 * blo(u0.z) + w1 * blo(u1.z) + w2 * blo(u2.z) + w3 * blo(u3.z);
        acc[5] += w0 * bhi(u0.z) + w1 * bhi(u1.z) + w2 * bhi(u2.z) + w3 * bhi(u3.z);
        acc[6] += w0 * blo(u0.w) + w1 * blo(u1.w) + w2 * blo(u2.w) + w3 * blo(u3.w);
        acc[7] += w0 * bhi(u0.w) + w1 * bhi(u1.w) + w2 * bhi(u2.w) + w3 * bhi(u3.w);
    }
    for (; e < deg; e++) {
        int s = srcp[e];
        float v = al_s[s * 4 + hl] + adh;
        v = (v > 0.f) ? v : NEG_SLOPE * v;
        float w = __expf(fminf(v, 60.f));
        ls += w;
        uint4 u = *(const uint4*)(hh + (size_t)s * 512 + lo8);
        acc[0] += w * blo(u.x); acc[1] += w * bhi(u.x);
        acc[2] += w * blo(u.y); acc[3] += w * bhi(u.y);
        acc[4] += w * blo(u.z); acc[5] += w * bhi(u.z);
        acc[6] += w * blo(u.w); acc[7] += w * bhi(u.w);
    }
    float il = 1.f / ls;
#pragma unroll
    for (int j = 0; j < 8; j++) acc[j] *= il;

    // head mean across lane groups 16/32/48
#pragma unroll
    for (int j = 0; j < 8; j++) {
        acc[j] += __shfl_xor(acc[j], 16);
        acc[j] += __shfl_xor(acc[j], 32);
    }
    int fb = (lane & 15) * 8;
    float4 bg0 = *(const float4*)(b_gat + fb);
    float4 bg1 = *(const float4*)(b_gat + fb + 4);
    float g[8];
    g[0] = acc[0] * 0.25f + bg0.x; g[1] = acc[1] * 0.25f + bg0.y;
    g[2] = acc[2] * 0.25f + bg0.z; g[3] = acc[3] * 0.25f + bg0.w;
    g[4] = acc[4] * 0.25f + bg1.x; g[5] = acc[5] * 0.25f + bg1.y;
    g[6] = acc[6] * 0.25f + bg1.z; g[7] = acc[7] * 0.25f + bg1.w;

    // LayerNorm stats within 16-lane group (replicated across groups)
    float s1 = 0.f;
#pragma unroll
    for (int j = 0; j < 8; j++) s1 += g[j];
#pragma unroll
    for (int off = 1; off < 16; off <<= 1) s1 += __shfl_xor(s1, off);
    float mu = s1 * (1.f / 128.f);
    float s2 = 0.f;
#pragma unroll
    for (int j = 0; j < 8; j++) { float d = g[j] - mu; s2 += d * d; }
#pragma unroll
    for (int off = 1; off < 16; off <<= 1) s2 += __shfl_xor(s2, off);
    float rstd = rsqrtf(s2 * (1.f / 128.f) + LN_EPS);

    if (lane < 16) {
        float4 lw0 = *(const float4*)(ln_w + fb);
        float4 lw1 = *(const float4*)(ln_w + fb + 4);
        float4 lb0 = *(const float4*)(ln_b + fb);
        float4 lb1 = *(const float4*)(ln_b + fb + 4);
        float4 hi0 = *(const float4*)(h_in + (size_t)n * DIM + fb);
        float4 hi1 = *(const float4*)(h_in + (size_t)n * DIM + fb + 4);
        float o[8];
        o[0] = fmaxf((g[0] - mu) * rstd * lw0.x + lb0.x, 0.f) + hi0.x;
        o[1] = fmaxf((g[1] - mu) * rstd * lw0.y + lb0.y, 0.f) + hi0.y;
        o[2] = fmaxf((g[2] - mu) * rstd * lw0.z + lb0.z, 0.f) + hi0.z;
        o[3] = fmaxf((g[3] - mu) * rstd * lw0.w + lb0.w, 0.f) + hi0.w;
        o[4] = fmaxf((g[4] - mu) * rstd * lw1.x + lb1.x, 0.f) + hi1.x;
        o[5] = fmaxf((g[5] - mu) * rstd * lw1.y + lb1.y, 0.f) + hi1.y;
        o[6] = fmaxf((g[6] - mu) * rstd * lw1.z + lb1.z, 0.f) + hi1.z;
        o[7] = fmaxf((g[7] - mu) * rstd * lw1.w + lb1.w, 0.f) + hi1.w;
        *(float4*)(h_out + (size_t)n * DIM + fb)     = make_float4(o[0], o[1], o[2], o[3]);
        *(float4*)(h_out + (size_t)n * DIM + fb + 4) = make_float4(o[4], o[5], o[6], o[7]);
        uint4 pb;
        pb.x = (unsigned)f2b(o[0]) | ((unsigned)f2b(o[1]) << 16);
        pb.y = (unsigned)f2b(o[2]) | ((unsigned)f2b(o[3]) << 16);
        pb.z = (unsigned)f2b(o[4]) | ((unsigned)f2b(o[5]) << 16);
        pb.w = (unsigned)f2b(o[6]) | ((unsigned)f2b(o[7]) << 16);
        *(uint4*)(h_out_bf + (size_t)n * DIM + fb) = pb;
    }
}

// ---------------------------------------------------------------------------
// Graph pooling: mean + max per graph (batch sorted -> binary search range)
// ---------------------------------------------------------------------------
__device__ int lower_bound_dev(const int* a, int n, int v) {
    int lo = 0, hi = n;
    while (lo < hi) { int mid = (lo + hi) >> 1; if (a[mid] < v) lo = mid + 1; else hi = mid; }
    return lo;
}

__global__ __launch_bounds__(512) void pool_kernel(const float* __restrict__ h,
                                                   const int* __restrict__ batch,
                                                   float* __restrict__ gmean,
                                                   float* __restrict__ gmax) {
    __shared__ float ssum[4][128];
    __shared__ float smax[4][128];
    __shared__ int bounds[2];
    int g = blockIdx.x;
    int tid = threadIdx.x;
    if (tid < 2) bounds[tid] = lower_bound_dev(batch, N_NODES, g + tid);
    __syncthreads();
    int lo = bounds[0], hi = bounds[1];
    int q = tid >> 7, d = tid & 127;
    float s = 0.f, m = -1e30f;
    for (int i = lo + q; i < hi; i += 4) {
        float v = h[(size_t)i * DIM + d];
        s += v; m = fmaxf(m, v);
    }
    ssum[q][d] = s; smax[q][d] = m;
    __syncthreads();
    if (tid < 128) {
        float S = ssum[0][d] + ssum[1][d] + ssum[2][d] + ssum[3][d];
        float M = fmaxf(fmaxf(smax[0][d], smax[1][d]), fmaxf(smax[2][d], smax[3][d]));
        int cnt = hi - lo;
        gmean[g * DIM + d] = S / fmaxf((float)cnt, 1.f);
        gmax[g * DIM + d]  = (cnt > 0) ? M : 0.f;
    }
}

// ---------------------------------------------------------------------------
// Fused tail per graph: TDA MLP -> concat -> sh1 -> sh2 -> 6 task heads.
// One 256-thread block per graph.
// ---------------------------------------------------------------------------
__global__ __launch_bounds__(256) void tail_kernel(
    const float* __restrict__ gmean, const float* __restrict__ gmax,
    const float* __restrict__ tda,
    const float* __restrict__ w_t1, const float* __restrict__ b_t1,
    const float* __restrict__ w_t2, const float* __restrict__ b_t2,
    const float* __restrict__ w_sh1, const float* __restrict__ b_sh1,
    const float* __restrict__ w_sh2, const float* __restrict__ b_sh2,
    const float* __restrict__ w_h1, const float* __restrict__ b_h1,
    const float* __restrict__ w_h2, const float* __restrict__ b_h2,
    float* __restrict__ out) {
    __shared__ float comb[320];
    __shared__ float tr[F_TDA];
    __shared__ float t1[64];
    __shared__ float s1o[256];
    __shared__ float s2o[128];
    __shared__ float prods[NTASK * 64];
    int g = blockIdx.x, tid = threadIdx.x;

    if (tid < 128) comb[tid] = gmean[g * 128 + tid];
    else           comb[tid] = gmax[g * 128 + (tid - 128)];
    if (tid < F_TDA) tr[tid] = tda[g * F_TDA + tid];
    __syncthreads();
    if (tid < 64) {
        float a = b_t1[tid];
#pragma unroll
        for (int k = 0; k < F_TDA; k++) a += tr[k] * w_t1[k * 64 + tid];
        t1[tid] = fmaxf(a, 0.f);
    }
    __syncthreads();
    if (tid < 64) {
        float a = b_t2[tid];
#pragma unroll
        for (int k = 0; k < 64; k++) a += t1[k] * w_t2[k * 64 + tid];
        comb[256 + tid] = fmaxf(a, 0.f);
    }
    __syncthreads();
    {
        float a = b_sh1[tid];
        for (int k = 0; k < 320; k++) a += comb[k] * w_sh1[k * 256 + tid];
        s1o[tid] = fmaxf(a, 0.f);
    }
    __syncthreads();
    if (tid < 128) {
        float a = b_sh2[tid];
        for (int k = 0; k < 256; k++) a += s1o[k] * w_sh2[k * 128 + tid];
        s2o[tid] = fmaxf(a, 0.f);
    }
    __syncthreads();
    for (int u = tid; u < NTASK * 64; u += 256) {
        int t = u >> 6, k = u & 63;
        float a = b_h1[t * 64 + k];
#pragma unroll 16
        for (int d = 0; d < 128; d++) a += s2o[d] * w_h1[(size_t)t * 8192 + d * 64 + k];
        prods[u] = fmaxf(a, 0.f) * w_h2[t * 64 + k];
    }
    __syncthreads();
    if (tid < NTASK) {
        float p = b_h2[tid];
#pragma unroll 16
        for (int k = 0; k < 64; k++) p += prods[tid * 64 + k];
        out[tid * 256 + g] = p;
    }
}

// ---------------------------------------------------------------------------
extern "C" void kernel_launch(void* const* d_in, const int* in_sizes, int n_in,
                              void* d_out, int out_size, void* d_ws, size_t ws_size,
                              hipStream_t stream) {
    const float* x        = (const float*)d_in[0];
    const int*   edge_idx = (const int*)  d_in[1];
    const int*   batch    = (const int*)  d_in[2];
    const float* tda      = (const float*)d_in[3];
    const float* w_in     = (const float*)d_in[4];
    const float* b_in     = (const float*)d_in[5];
    const float* w_gat    = (const float*)d_in[6];
    const float* a_src    = (const float*)d_in[7];
    const float* a_dst    = (const float*)d_in[8];
    const float* b_gat    = (const float*)d_in[9];
    const float* ln_w     = (const float*)d_in[10];
    const float* ln_b     = (const float*)d_in[11];
    const float* w_tda1   = (const float*)d_in[12];
    const float* b_tda1   = (const float*)d_in[13];
    const float* w_tda2   = (const float*)d_in[14];
    const float* b_tda2   = (const float*)d_in[15];
    const float* w_sh1    = (const float*)d_in[16];
    const float* b_sh1    = (const float*)d_in[17];
    const float* w_sh2    = (const float*)d_in[18];
    const float* b_sh2    = (const float*)d_in[19];
    const float* w_h1     = (const float*)d_in[20];
    const float* b_h1     = (const float*)d_in[21];
    const float* w_h2     = (const float*)d_in[22];
    const float* b_h2     = (const float*)d_in[23];
    float* out = (float*)d_out;

    // workspace carve-up (256B aligned)
    size_t off = 0;
    auto alloc = [&](size_t bytes) -> void* {
        void* p = (char*)d_ws + off;
        off += (bytes + 255) & ~(size_t)255;
        return p;
    };
    float*          h_a    = (float*)alloc((size_t)N_NODES * DIM * 4);
    float*          h_b    = (float*)alloc((size_t)N_NODES * DIM * 4);
    unsigned short* hb_a   = (unsigned short*)alloc((size_t)N_NODES * DIM * 2);
    unsigned short* hb_b   = (unsigned short*)alloc((size_t)N_NODES * DIM * 2);
    unsigned short* hh     = (unsigned short*)alloc((size_t)N_NODES * NHEAD * DIM * 2);
    unsigned short* wt     = (unsigned short*)alloc((size_t)NLAYER * 512 * 128 * 2);
    float*          al_s   = (float*)alloc((size_t)N_NODES * NHEAD * 4);
    float*          al_d   = (float*)alloc((size_t)N_NODES * NHEAD * 4);
    int*            counts = (int*)  alloc((size_t)N_NODES * 4);
    int*            cursor = (int*)  alloc((size_t)N_NODES * 4);
    int*            rowptr = (int*)  alloc((size_t)(N_NODES + 1) * 4);
    int*            csrsrc = (int*)  alloc((size_t)E_TOTAL * 4);
    float*          gmean  = (float*)alloc((size_t)N_GRAPHS * DIM * 4);
    float*          gmax   = (float*)alloc((size_t)N_GRAPHS * DIM * 4);

    // CSR build
    hipMemsetAsync(counts, 0, (size_t)N_NODES * 4, stream);
    int eb = (E_TOTAL + 255) / 256;
    count_kernel<<<eb, 256, 0, stream>>>(edge_idx, counts);
    scan_kernel<<<(N_NODES + 1023) / 1024, 1024, 0, stream>>>(counts, rowptr, cursor);
    scatter_kernel<<<eb, 256, 0, stream>>>(edge_idx, cursor, csrsrc);

    // weight transpose (all layers), input projection
    wtrans_kernel<<<(NLAYER * 512 * 128 + 255) / 256, 256, 0, stream>>>(w_gat, wt);
    proj_in_kernel<<<N_NODES, 128, 0, stream>>>(x, w_in, b_in, h_a, hb_a);

    float* h_cur = h_a;  unsigned short* hb_cur = hb_a;
    float* h_nxt = h_b;  unsigned short* hb_nxt = hb_b;
    for (int l = 0; l < NLAYER; l++) {
        gemm_mfma_kernel<<<dim3(4, (N_NODES + 63) / 64), 256, 0, stream>>>(
            hb_cur, wt + (size_t)l * 512 * 128,
            a_src + (size_t)l * NHEAD * DIM, a_dst + (size_t)l * NHEAD * DIM,
            hh, al_s, al_d, N_NODES);
        gat_aggregate_kernel<<<(N_NODES + 3) / 4, 256, 0, stream>>>(
            hh, al_s, al_d, rowptr, csrsrc, h_cur,
            b_gat + (size_t)l * DIM, ln_w + (size_t)l * DIM, ln_b + (size_t)l * DIM,
            h_nxt, hb_nxt);
        float* t = h_cur; h_cur = h_nxt; h_nxt = t;
        unsigned short* tb = hb_cur; hb_cur = hb_nxt; hb_nxt = tb;
    }

    // pooling + fused tail
    pool_kernel<<<N_GRAPHS, 512, 0, stream>>>(h_cur, batch, gmean, gmax);
    tail_kernel<<<N_GRAPHS, 256, 0, stream>>>(
        gmean, gmax, tda, w_tda1, b_tda1, w_tda2, b_tda2,
        w_sh1, b_sh1, w_sh2, b_sh2, w_h1, b_h1, w_h2, b_h2, out);
}